// Round 8
// baseline (137.482 us; speedup 1.0000x reference)
//
#include <hip/hip_runtime.h>
#include <hip/hip_bf16.h>
#include <math.h>

#define BATCH 8
#define SEQ   2048
#define CH    256
#define NH    4
#define HD    64
#define NQB   (SEQ / 64)      // 32 query tiles of 64
// Q pre-scale: 64^-0.5 * log2(e)  (softmax runs in exp2 domain)
#define QSCALE 0.18033688011112042f

typedef short  bfrag __attribute__((ext_vector_type(8)));  // 8 bf16 (4 VGPRs)
typedef float  ffrag __attribute__((ext_vector_type(4)));  // 4 fp32 acc
typedef unsigned short ushort_t;
typedef unsigned int u32;

__device__ __forceinline__ unsigned short f2bf(float f) {
    union { float f; unsigned int u; } v; v.f = f;
    unsigned int r = v.u + 0x7FFF + ((v.u >> 16) & 1);   // RNE
    return (unsigned short)(r >> 16);
}
__device__ __forceinline__ unsigned int pack2(float a, float b) {
    const __hip_bfloat162 p = __float22bfloat162_rn(make_float2(a, b));
    return *(const unsigned int*)&p;
}
// async global->LDS, 16B/lane. LDS base must be wave-uniform; global per-lane.
__device__ __forceinline__ void gload16(const ushort_t* g, ushort_t* l) {
    __builtin_amdgcn_global_load_lds(
        (const __attribute__((address_space(1))) u32*)g,
        (__attribute__((address_space(3))) u32*)l, 16, 0, 0);
}

// ---------------------------------------------------------------------------
// Prep: x -> bf16 [M][C] (vectorized x8), Wqkv/Wproj -> transposed bf16.
// xb aliases attn_b in workspace (dead until attn writes, which is post-qkv).
// ---------------------------------------------------------------------------
#define WQN (CH * 3 * CH)            // 196608
#define WPN (CH * CH)                // 65536
#define XN  (BATCH * SEQ * CH)       // 4,194,304
#define XN8 (XN / 8)                 // 524,288

__global__ __launch_bounds__(256) void prep_kernel(
    const float* __restrict__ x,
    const float* __restrict__ Wqkv, const float* __restrict__ Wproj,
    ushort_t* __restrict__ xb,
    ushort_t* __restrict__ WqkvT, ushort_t* __restrict__ WprojT) {
    const int fid = blockIdx.x * 256 + threadIdx.x;
    if (fid < XN8) {
        const float4 a = *(const float4*)&x[(size_t)fid * 8];
        const float4 c = *(const float4*)&x[(size_t)fid * 8 + 4];
        uint4 pk;
        pk.x = pack2(a.x, a.y); pk.y = pack2(a.z, a.w);
        pk.z = pack2(c.x, c.y); pk.w = pack2(c.z, c.w);
        *(uint4*)&xb[(size_t)fid * 8] = pk;
    } else {
        const int id = fid - XN8;
        if (id < WQN) {
            const int n = id >> 8, k = id & 255;
            WqkvT[n * CH + k] = f2bf(Wqkv[k * (3 * CH) + n]);
        } else if (id < WQN + WPN) {
            const int i = id - WQN;
            const int n = i >> 8, k = i & 255;
            WprojT[n * CH + k] = f2bf(Wproj[k * CH + n]);
        }
    }
}

// ---------------------------------------------------------------------------
// QKV MFMA GEMM: xb bf16 @ WqkvT^T + bqkv -> bf16 Q(*QSCALE),K [BH,T,D],
// V^T [BH,D,T]. 128x128 tile, 4 waves each 64x64, BK=64.
// Staging via global_load_lds width=16 (async, no VGPR round-trip); linear
// LDS + pre-swizzled global source + swizzled fragment reads (verified R7).
// ---------------------------------------------------------------------------
#define GLS 72   // LDS row stride in ushorts (proj kernel only)

__global__ __launch_bounds__(256) void qkv_mfma_kernel(
    const ushort_t* __restrict__ xb, const ushort_t* __restrict__ Wt,
    const float* __restrict__ bias,
    ushort_t* __restrict__ Qb, ushort_t* __restrict__ Kb,
    ushort_t* __restrict__ Vtb) {
    __shared__ ushort_t smem[128 * 136];   // As[0,8K) Bs[8K,16K) ; epilogue T[128][136]
    ushort_t* As = smem;
    ushort_t* Bs = smem + 128 * 64;

    const int tid = threadIdx.x;
    const int wv  = tid >> 6;
    const int ln  = tid & 63;
    const int l15 = ln & 15;
    const int l4  = ln >> 4;
    const int e   = l15 & 7;
    const int wr  = wv >> 1;          // wave row 0..1
    const int wc  = wv & 1;           // wave col 0..1
    const int n0  = blockIdx.x * 128;
    const int m0  = blockIdx.y * 128;

    // staging geometry: each wave moves 4x1KB chunks per matrix per K-step.
    const int grow = ln >> 3;                         // row within 8-row chunk
    const int swz  = ((ln & 7) ^ grow) * 8;           // pre-swizzled src chunk

    ffrag acc[4][4];
    #pragma unroll
    for (int i = 0; i < 4; i++)
        #pragma unroll
        for (int j = 0; j < 4; j++) acc[i][j] = (ffrag){0.f, 0.f, 0.f, 0.f};

    for (int k0 = 0; k0 < CH; k0 += 64) {
        #pragma unroll
        for (int i = 0; i < 4; i++) {
            const int rowA = (i * 4 + wv) * 8 + grow;       // 0..127
            gload16(&xb[(size_t)(m0 + rowA) * CH + k0 + swz], &As[(i * 4 + wv) * 512]);
            gload16(&Wt[(size_t)(n0 + rowA) * CH + k0 + swz], &Bs[(i * 4 + wv) * 512]);
        }
        __syncthreads();   // drains vmcnt (incl. global_load_lds) at barrier
        #pragma unroll
        for (int kk = 0; kk < 64; kk += 32) {
            bfrag a[4], b[4];
            #pragma unroll
            for (int i = 0; i < 4; i++) {
                const int R = wr * 64 + i * 16 + l15;       // R&7 == e
                a[i] = *(const bfrag*)&As[R * 64 + ((((kk >> 3) + l4) ^ e) * 8)];
            }
            #pragma unroll
            for (int j = 0; j < 4; j++) {
                const int R = wc * 64 + j * 16 + l15;       // R&7 == e
                b[j] = *(const bfrag*)&Bs[R * 64 + ((((kk >> 3) + l4) ^ e) * 8)];
            }
            #pragma unroll
            for (int i = 0; i < 4; i++)
                #pragma unroll
                for (int j = 0; j < 4; j++)
                    acc[i][j] = __builtin_amdgcn_mfma_f32_16x16x32_bf16(a[i], b[j], acc[i][j], 0, 0, 0);
        }
        __syncthreads();
    }

    const int mat = n0 >> 8;                 // block-uniform: 0=Q 1=K 2=V
    const int b   = m0 >> 11;                // block-uniform
    const int t0  = m0 & (SEQ - 1);
    ushort_t (*T)[136] = (ushort_t(*)[136])smem;

    if (mat < 2) {
        // Q/K: transpose to T[t_local][n_local], then coalesced [T,D] stores.
        const float sc = (mat == 0) ? QSCALE : 1.0f;
        #pragma unroll
        for (int j = 0; j < 4; j++) {
            const int n_local = wc * 64 + j * 16 + l15;
            const float bj = bias[n0 + n_local];
            #pragma unroll
            for (int i = 0; i < 4; i++) {
                const int m_base = wr * 64 + i * 16 + l4 * 4;
                #pragma unroll
                for (int r = 0; r < 4; r++)
                    T[m_base + r][n_local] = f2bf((acc[i][j][r] + bj) * sc);
            }
        }
        __syncthreads();
        ushort_t* dst = (mat == 0) ? Qb : Kb;
        #pragma unroll
        for (int rr = 0; rr < 8; rr++) {
            const int fid = tid + rr * 256;
            const int row = fid >> 4;            // t_local 0..127
            const int c8  = (fid & 15) * 8;      // n_local chunk
            const int n_glob = n0 + c8;
            const int h = (n_glob >> 6) & 3;
            const int d = n_glob & 63;
            *(uint4*)&dst[((size_t)((b * NH + h) * SEQ) + t0 + row) * HD + d] =
                *(const uint4*)&T[row][c8];
        }
    } else {
        // V: transpose to T[n_local][m_local], then coalesced [D,T] stores.
        #pragma unroll
        for (int j = 0; j < 4; j++) {
            const int n_local = wc * 64 + j * 16 + l15;
            const float bj = bias[n0 + n_local];
            #pragma unroll
            for (int i = 0; i < 4; i++) {
                const int m_base = wr * 64 + i * 16 + l4 * 4;
                ushort4 pk;
                pk.x = f2bf(acc[i][j][0] + bj);
                pk.y = f2bf(acc[i][j][1] + bj);
                pk.z = f2bf(acc[i][j][2] + bj);
                pk.w = f2bf(acc[i][j][3] + bj);
                *(ushort4*)&T[n_local][m_base] = pk;
            }
        }
        __syncthreads();
        #pragma unroll
        for (int rr = 0; rr < 8; rr++) {
            const int fid = tid + rr * 256;
            const int row = fid >> 4;            // n_local 0..127
            const int c8  = (fid & 15) * 8;      // m_local chunk
            const int n_glob = n0 + row;
            const int h = (n_glob >> 6) & 3;
            const int d = n_glob & 63;
            *(uint4*)&Vtb[(size_t)((b * NH + h) * HD + d) * SEQ + t0 + c8] =
                *(const uint4*)&T[row][c8];
        }
    }
}

// ---------------------------------------------------------------------------
// MFMA flash attention (causal), S^T form, exp2 STATIC-MAX softmax,
// O^T = V^T * P^T — R2 double-buffer structure, but K/V staging now via
// global_load_lds DMA (no reg round-trip, no ds_write, 16 fewer VGPRs).
// Layout equivalence: linear DMA dest + source chunk ^= (lane>>3) reproduces
// LDS[row][c] = G[row][c^(row&7)] exactly (srow&7 == lane>>3 for all waves),
// so all fragment read offsets are unchanged. Double-buffer handshake is the
// barrier's vmcnt drain: STAGE(kt+1) is issued right after the barrier into
// the buffer not being read; the next barrier guarantees completion.
// ---------------------------------------------------------------------------
__global__ __launch_bounds__(256, 4) void attn_mfma_kernel(
    const ushort_t* __restrict__ Qb, const ushort_t* __restrict__ Kb,
    const ushort_t* __restrict__ Vtb, ushort_t* __restrict__ out) {
    __shared__ ushort_t Ps[64 * 64];       // P tiles (wave-private 16-row bands)
    __shared__ ushort_t KV[4 * 64 * 64];   // K0 | K1 | V0 | V1 (8 KB each)

    const int tid = threadIdx.x;
    const int wv  = tid >> 6;
    const int ln  = tid & 63;
    const int l15 = ln & 15;
    const int l4  = ln >> 4;
    const int e   = l15 & 7;

    const int L  = blockIdx.x;
    const int g  = L & 255;
    const int s4 = L >> 8;               // dispatch wave 0..3
    const int v  = g >> 5;               // 0..7
    // longest-first; per-CU slot set {31-v, 16+v, 15-v, v} sums to 66 iters
    const int qb = (s4 == 0) ? (31 - v) : (s4 == 1) ? (16 + v) : (s4 == 2) ? (15 - v) : v;
    const int bh = g & 31;
    const int b  = bh >> 2;
    const int h  = bh & 3;

    // ---- Q fragments straight from global (B-operand: B[n=q][k]) ----
    const ushort_t* Qp = Qb + ((size_t)(bh * SEQ + qb * 64 + wv * 16 + l15)) * HD + l4 * 8;
    const bfrag bq0 = *(const bfrag*)Qp;
    const bfrag bq1 = *(const bfrag*)(Qp + 32);

    // ---- DMA staging geometry ----
    const ushort_t* Kbase = Kb  + (size_t)bh * SEQ * HD;
    const ushort_t* Vbase = Vtb + (size_t)bh * HD * SEQ;
    const int srow   = tid >> 3;                       // 0..31
    const int schunk = ((tid & 7) ^ (srow & 7)) * 8;   // pre-swizzled src chunk
    const int goffK  = srow * 64 + schunk;             // K global (ushorts)
    const int goffV  = srow * SEQ + schunk;            // V global
    ushort_t* const dstW = &KV[wv * 512];              // wave-uniform DMA base

    // ---- fragment read offsets (precomputed, swizzled; layout unchanged) --
    const int kf0 = l15 * 64 + ((l4 ^ e) * 8);   // + n*1024 ; ^32 for k-chunk 1
    const int pf0 = (wv * 16 + l15) * 64 + ((l4 ^ e) * 8);
    const int pp  = e >> 1;
    const int pwb = (wv * 16 + l15) * 64 + (((l4 >> 1) ^ (e & 1)) * 8) + (l4 & 1) * 4;

    // ---- prologue: DMA tile 0 into buffer 0 ----
    gload16(Kbase + goffK,            dstW);
    gload16(Kbase + goffK + 2048,     dstW + 2048);
    gload16(Vbase + goffV,            dstW + 8192);
    gload16(Vbase + goffV + 32 * SEQ, dstW + 8192 + 2048);

    ffrag o[4];   // O^T accumulator: o[n][r] = O^T[d = n*16+l4*4+r][q = l15]
    #pragma unroll
    for (int n = 0; n < 4; n++) o[n] = (ffrag){0.f, 0.f, 0.f, 0.f};
    float l_q = 0.f;                      // in-lane partial; shuffles at end
    const int qg_l = qb * 64 + wv * 16 + l15;

    for (int kt = 0; kt <= qb; kt++) {
        __syncthreads();   // (a) prior iter's reads done; (b) DMA tile kt landed

        if (kt < qb) {     // DMA tile kt+1 into the buffer NOT read this iter
            const int kb = ((kt + 1) & 1) * 4096;
            const ushort_t* Kp = Kbase + (kt + 1) * 4096;
            const ushort_t* Vp = Vbase + (kt + 1) * 64;
            gload16(Kp + goffK,            dstW + kb);
            gload16(Kp + goffK + 2048,     dstW + kb + 2048);
            gload16(Vp + goffV,            dstW + 8192 + kb);
            gload16(Vp + goffV + 32 * SEQ, dstW + 8192 + kb + 2048);
        }

        const ushort_t* Kbuf = KV + (kt & 1) * 4096;
        const ushort_t* Vbuf = KV + 8192 + (kt & 1) * 4096;

        // ---- S^T = K Q^T : s[n][r] = S[q=l15][k = n*16 + l4*4 + r] ----
        ffrag s[4];
        __builtin_amdgcn_s_setprio(1);
        #pragma unroll
        for (int n = 0; n < 4; n++) {
            const bfrag ak0 = *(const bfrag*)&Kbuf[n * 1024 + kf0];
            const bfrag ak1 = *(const bfrag*)&Kbuf[n * 1024 + (kf0 ^ 32)];
            ffrag z = (ffrag){0.f, 0.f, 0.f, 0.f};
            z = __builtin_amdgcn_mfma_f32_16x16x32_bf16(ak0, bq0, z, 0, 0, 0);
            z = __builtin_amdgcn_mfma_f32_16x16x32_bf16(ak1, bq1, z, 0, 0, 0);
            s[n] = z;
        }
        __builtin_amdgcn_s_setprio(0);
        if (kt == qb) {   // causal mask on the diagonal tile
            #pragma unroll
            for (int n = 0; n < 4; n++)
                #pragma unroll
                for (int r = 0; r < 4; r++)
                    if (kt * 64 + n * 16 + l4 * 4 + r > qg_l) s[n][r] = -INFINITY;
        }

        // ---- softmax (exp2 domain, static max): p = exp2(S'); exp2(-inf)=0 --
        #pragma unroll
        for (int n = 0; n < 4; n++)
            #pragma unroll
            for (int r = 0; r < 4; r++) {
                const float p = __builtin_amdgcn_exp2f(s[n][r]);
                s[n][r] = p;
                l_q += p;
            }

        // ---- pack P (bf16, A/B-layout rows q, swizzled, wave-private) ----
        #pragma unroll
        for (int n = 0; n < 4; n++) {
            uint2 pk;
            pk.x = pack2(s[n][0], s[n][1]);
            pk.y = pack2(s[n][2], s[n][3]);
            *(uint2*)&Ps[pwb + ((n ^ pp) << 4)] = pk;
        }

        // ---- O^T += V^T @ P^T ----
        const bfrag ap0 = *(const bfrag*)&Ps[pf0];
        const bfrag ap1 = *(const bfrag*)&Ps[pf0 ^ 32];
        __builtin_amdgcn_s_setprio(1);
        #pragma unroll
        for (int n = 0; n < 4; n++) {
            const bfrag av0 = *(const bfrag*)&Vbuf[n * 1024 + kf0];
            const bfrag av1 = *(const bfrag*)&Vbuf[n * 1024 + (kf0 ^ 32)];
            o[n] = __builtin_amdgcn_mfma_f32_16x16x32_bf16(av0, ap0, o[n], 0, 0, 0);
            o[n] = __builtin_amdgcn_mfma_f32_16x16x32_bf16(av1, ap1, o[n], 0, 0, 0);
        }
        __builtin_amdgcn_s_setprio(0);
    }

    // ---- deferred l reduction: l4-group partials are disjoint k-subsets ----
    l_q += __shfl_xor(l_q, 16);
    l_q += __shfl_xor(l_q, 32);

    // ---- normalize + store O (bf16, [B,T,C]): in-lane 1/l, vector stores ----
    const float li = 1.0f / l_q;
    const int tq = qb * 64 + wv * 16 + l15;        // this lane's q row
    ushort_t* op = out + (size_t)(b * SEQ + tq) * CH + h * HD;
    #pragma unroll
    for (int n = 0; n < 4; n++) {
        ushort4 pk;
        pk.x = f2bf(o[n][0] * li);
        pk.y = f2bf(o[n][1] * li);
        pk.z = f2bf(o[n][2] * li);
        pk.w = f2bf(o[n][3] * li);
        *(ushort4*)&op[n * 16 + l4 * 4] = pk;      // d = n*16 + l4*4 .. +3
    }
}

// ---------------------------------------------------------------------------
// Proj MFMA GEMM: attn_b @ WprojT^T + bproj -> fp32 out.
// 128x64 tile (4 waves: 2x2, each 64x32), grid 512 -> 2 blocks/CU.
// Epilogue now transposes through LDS -> coalesced float4 stores (8/thread)
// instead of 32 scalar fp32 stores at 64B segment granularity.
// ---------------------------------------------------------------------------
__global__ __launch_bounds__(256) void proj_mfma_kernel(
    const ushort_t* __restrict__ Ab, const ushort_t* __restrict__ Wt,
    const float* __restrict__ bias, float* __restrict__ O) {
    __shared__ __align__(16) char smem_raw[128 * 68 * 4];   // 34.8 KB
    ushort_t* As = (ushort_t*)smem_raw;
    ushort_t* Bs = As + 128 * GLS;

    const int tid = threadIdx.x;
    const int wv  = tid >> 6;
    const int ln  = tid & 63;
    const int l15 = ln & 15;
    const int l4  = ln >> 4;
    const int wr  = wv >> 1;          // 0..1 -> 64-row band
    const int wc  = wv & 1;           // 0..1 -> 32-col band
    const int n0  = blockIdx.x * 64;
    const int m0  = blockIdx.y * 128;

    ffrag acc[4][2];
    #pragma unroll
    for (int i = 0; i < 4; i++)
        #pragma unroll
        for (int j = 0; j < 2; j++) acc[i][j] = (ffrag){0.f, 0.f, 0.f, 0.f};

    for (int k0 = 0; k0 < CH; k0 += 64) {
        #pragma unroll
        for (int r = 0; r < 4; r++) {   // A: 128x64 = 1024 chunks
            const int fid = tid + r * 256;
            const int row = fid >> 3, c8 = (fid & 7) * 8;
            *(uint4*)&As[row * GLS + c8] = *(const uint4*)&Ab[(size_t)(m0 + row) * CH + k0 + c8];
        }
        #pragma unroll
        for (int r = 0; r < 2; r++) {   // B: 64x64 = 512 chunks
            const int fid = tid + r * 256;
            const int row = fid >> 3, c8 = (fid & 7) * 8;
            *(uint4*)&Bs[row * GLS + c8] = *(const uint4*)&Wt[(n0 + row) * CH + k0 + c8];
        }
        __syncthreads();
        #pragma unroll
        for (int kk = 0; kk < 64; kk += 32) {
            bfrag a[4], b[2];
            #pragma unroll
            for (int i = 0; i < 4; i++)
                a[i] = *(const bfrag*)&As[(wr * 64 + i * 16 + l15) * GLS + kk + l4 * 8];
            #pragma unroll
            for (int j = 0; j < 2; j++)
                b[j] = *(const bfrag*)&Bs[(wc * 32 + j * 16 + l15) * GLS + kk + l4 * 8];
            #pragma unroll
            for (int i = 0; i < 4; i++)
                #pragma unroll
                for (int j = 0; j < 2; j++)
                    acc[i][j] = __builtin_amdgcn_mfma_f32_16x16x32_bf16(a[i], b[j], acc[i][j], 0, 0, 0);
        }
        __syncthreads();
    }

    // ---- epilogue: transpose through LDS, coalesced float4 stores ----
    float (*Tf)[68] = (float(*)[68])smem_raw;   // last loop iter ended in barrier
    #pragma unroll
    for (int j = 0; j < 2; j++) {
        const int n_local = wc * 32 + j * 16 + l15;
        const float bj = bias[n0 + n_local];
        #pragma unroll
        for (int i = 0; i < 4; i++) {
            const int m_base = wr * 64 + i * 16 + l4 * 4;
            #pragma unroll
            for (int r = 0; r < 4; r++)
                Tf[m_base + r][n_local] = acc[i][j][r] + bj;
        }
    }
    __syncthreads();
    #pragma unroll
    for (int rr = 0; rr < 8; rr++) {
        const int fid = tid + rr * 256;
        const int row = fid >> 4;           // m_local 0..127
        const int c4  = (fid & 15) * 4;     // n_local chunk of 4 floats
        *(float4*)&O[(size_t)(m0 + row) * CH + n0 + c4] =
            *(const float4*)&Tf[row][c4];
    }
}

extern "C" void kernel_launch(void* const* d_in, const int* in_sizes, int n_in,
                              void* d_out, int out_size, void* d_ws, size_t ws_size,
                              hipStream_t stream) {
    const float* x     = (const float*)d_in[0];
    const float* Wqkv  = (const float*)d_in[1];
    const float* bqkv  = (const float*)d_in[2];
    const float* Wproj = (const float*)d_in[3];
    const float* bproj = (const float*)d_in[4];
    float* out = (float*)d_out;

    const size_t BHTD = (size_t)BATCH * NH * SEQ * HD;   // 4,194,304
    ushort_t* WqkvT  = (ushort_t*)d_ws;
    ushort_t* WprojT = WqkvT + (size_t)3 * CH * CH;
    ushort_t* Qb     = WprojT + (size_t)CH * CH;
    ushort_t* Kb     = Qb + BHTD;
    ushort_t* Vtb    = Kb + BHTD;
    ushort_t* attn_b = Vtb + BHTD;
    ushort_t* xb     = attn_b;          // alias: xb dead before attn writes

    const int M = BATCH * SEQ;   // 16384

    {
        const int total = XN8 + WQN + WPN;          // 786,432
        prep_kernel<<<(total + 255) / 256, 256, 0, stream>>>(x, Wqkv, Wproj, xb, WqkvT, WprojT);
    }
    {
        dim3 grid((3 * CH) / 128, M / 128);
        qkv_mfma_kernel<<<grid, 256, 0, stream>>>(xb, WqkvT, bqkv, Qb, Kb, Vtb);
    }
    {
        attn_mfma_kernel<<<dim3(NQB * BATCH * NH), 256, 0, stream>>>(Qb, Kb, Vtb, attn_b);
    }
    {
        dim3 grid(CH / 64, M / 128);
        proj_mfma_kernel<<<grid, 256, 0, stream>>>(attn_b, WprojT, bproj, out);
    }
}

// Round 9
// 132.591 us; speedup vs baseline: 1.0369x; 1.0369x over previous
//
#include <hip/hip_runtime.h>
#include <hip/hip_bf16.h>
#include <math.h>

#define BATCH 8
#define SEQ   2048
#define CH    256
#define NH    4
#define HD    64
#define NQB   (SEQ / 64)      // 32 query tiles of 64
// Q pre-scale: 64^-0.5 * log2(e)  (softmax runs in exp2 domain)
#define QSCALE 0.18033688011112042f

typedef short  bfrag __attribute__((ext_vector_type(8)));  // 8 bf16 (4 VGPRs)
typedef float  ffrag __attribute__((ext_vector_type(4)));  // 4 fp32 acc
typedef unsigned short ushort_t;
typedef unsigned int u32;

__device__ __forceinline__ unsigned short f2bf(float f) {
    union { float f; unsigned int u; } v; v.f = f;
    unsigned int r = v.u + 0x7FFF + ((v.u >> 16) & 1);   // RNE
    return (unsigned short)(r >> 16);
}
__device__ __forceinline__ unsigned int pack2(float a, float b) {
    const __hip_bfloat162 p = __float22bfloat162_rn(make_float2(a, b));
    return *(const unsigned int*)&p;
}
// async global->LDS, 16B/lane. LDS base must be wave-uniform; global per-lane.
__device__ __forceinline__ void gload16(const ushort_t* g, ushort_t* l) {
    __builtin_amdgcn_global_load_lds(
        (const __attribute__((address_space(1))) u32*)g,
        (__attribute__((address_space(3))) u32*)l, 16, 0, 0);
}

// ---------------------------------------------------------------------------
// Prep: x -> bf16 [M][C] (vectorized x8), Wqkv/Wproj -> transposed bf16.
// xb aliases attn_b in workspace (dead until attn writes, which is post-qkv).
// ---------------------------------------------------------------------------
#define WQN (CH * 3 * CH)            // 196608
#define WPN (CH * CH)                // 65536
#define XN  (BATCH * SEQ * CH)       // 4,194,304
#define XN8 (XN / 8)                 // 524,288

__global__ __launch_bounds__(256) void prep_kernel(
    const float* __restrict__ x,
    const float* __restrict__ Wqkv, const float* __restrict__ Wproj,
    ushort_t* __restrict__ xb,
    ushort_t* __restrict__ WqkvT, ushort_t* __restrict__ WprojT) {
    const int fid = blockIdx.x * 256 + threadIdx.x;
    if (fid < XN8) {
        const float4 a = *(const float4*)&x[(size_t)fid * 8];
        const float4 c = *(const float4*)&x[(size_t)fid * 8 + 4];
        uint4 pk;
        pk.x = pack2(a.x, a.y); pk.y = pack2(a.z, a.w);
        pk.z = pack2(c.x, c.y); pk.w = pack2(c.z, c.w);
        *(uint4*)&xb[(size_t)fid * 8] = pk;
    } else {
        const int id = fid - XN8;
        if (id < WQN) {
            const int n = id >> 8, k = id & 255;
            WqkvT[n * CH + k] = f2bf(Wqkv[k * (3 * CH) + n]);
        } else if (id < WQN + WPN) {
            const int i = id - WQN;
            const int n = i >> 8, k = i & 255;
            WprojT[n * CH + k] = f2bf(Wproj[k * CH + n]);
        }
    }
}

// ---------------------------------------------------------------------------
// QKV MFMA GEMM: xb bf16 @ WqkvT^T + bqkv -> bf16 Q(*QSCALE),K [BH,T,D],
// V^T [BH,D,T]. 128x128 tile, 4 waves each 64x64, BK=64.
// Staging via global_load_lds width=16 (async, no VGPR round-trip); linear
// LDS + pre-swizzled global source + swizzled fragment reads (verified R7).
// ---------------------------------------------------------------------------
#define GLS 72   // LDS row stride in ushorts (proj kernel only)

__global__ __launch_bounds__(256) void qkv_mfma_kernel(
    const ushort_t* __restrict__ xb, const ushort_t* __restrict__ Wt,
    const float* __restrict__ bias,
    ushort_t* __restrict__ Qb, ushort_t* __restrict__ Kb,
    ushort_t* __restrict__ Vtb) {
    __shared__ ushort_t smem[128 * 136];   // As[0,8K) Bs[8K,16K) ; epilogue T[128][136]
    ushort_t* As = smem;
    ushort_t* Bs = smem + 128 * 64;

    const int tid = threadIdx.x;
    const int wv  = tid >> 6;
    const int ln  = tid & 63;
    const int l15 = ln & 15;
    const int l4  = ln >> 4;
    const int e   = l15 & 7;
    const int wr  = wv >> 1;          // wave row 0..1
    const int wc  = wv & 1;           // wave col 0..1
    const int n0  = blockIdx.x * 128;
    const int m0  = blockIdx.y * 128;

    // staging geometry: each wave moves 4x1KB chunks per matrix per K-step.
    const int grow = ln >> 3;                         // row within 8-row chunk
    const int swz  = ((ln & 7) ^ grow) * 8;           // pre-swizzled src chunk

    ffrag acc[4][4];
    #pragma unroll
    for (int i = 0; i < 4; i++)
        #pragma unroll
        for (int j = 0; j < 4; j++) acc[i][j] = (ffrag){0.f, 0.f, 0.f, 0.f};

    for (int k0 = 0; k0 < CH; k0 += 64) {
        #pragma unroll
        for (int i = 0; i < 4; i++) {
            const int rowA = (i * 4 + wv) * 8 + grow;       // 0..127
            gload16(&xb[(size_t)(m0 + rowA) * CH + k0 + swz], &As[(i * 4 + wv) * 512]);
            gload16(&Wt[(size_t)(n0 + rowA) * CH + k0 + swz], &Bs[(i * 4 + wv) * 512]);
        }
        __syncthreads();   // drains vmcnt (incl. global_load_lds) at barrier
        #pragma unroll
        for (int kk = 0; kk < 64; kk += 32) {
            bfrag a[4], b[4];
            #pragma unroll
            for (int i = 0; i < 4; i++) {
                const int R = wr * 64 + i * 16 + l15;       // R&7 == e
                a[i] = *(const bfrag*)&As[R * 64 + ((((kk >> 3) + l4) ^ e) * 8)];
            }
            #pragma unroll
            for (int j = 0; j < 4; j++) {
                const int R = wc * 64 + j * 16 + l15;       // R&7 == e
                b[j] = *(const bfrag*)&Bs[R * 64 + ((((kk >> 3) + l4) ^ e) * 8)];
            }
            #pragma unroll
            for (int i = 0; i < 4; i++)
                #pragma unroll
                for (int j = 0; j < 4; j++)
                    acc[i][j] = __builtin_amdgcn_mfma_f32_16x16x32_bf16(a[i], b[j], acc[i][j], 0, 0, 0);
        }
        __syncthreads();
    }

    const int mat = n0 >> 8;                 // block-uniform: 0=Q 1=K 2=V
    const int b   = m0 >> 11;                // block-uniform
    const int t0  = m0 & (SEQ - 1);
    ushort_t (*T)[136] = (ushort_t(*)[136])smem;

    if (mat < 2) {
        // Q/K: transpose to T[t_local][n_local], then coalesced [T,D] stores.
        const float sc = (mat == 0) ? QSCALE : 1.0f;
        #pragma unroll
        for (int j = 0; j < 4; j++) {
            const int n_local = wc * 64 + j * 16 + l15;
            const float bj = bias[n0 + n_local];
            #pragma unroll
            for (int i = 0; i < 4; i++) {
                const int m_base = wr * 64 + i * 16 + l4 * 4;
                #pragma unroll
                for (int r = 0; r < 4; r++)
                    T[m_base + r][n_local] = f2bf((acc[i][j][r] + bj) * sc);
            }
        }
        __syncthreads();
        ushort_t* dst = (mat == 0) ? Qb : Kb;
        #pragma unroll
        for (int rr = 0; rr < 8; rr++) {
            const int fid = tid + rr * 256;
            const int row = fid >> 4;            // t_local 0..127
            const int c8  = (fid & 15) * 8;      // n_local chunk
            const int n_glob = n0 + c8;
            const int h = (n_glob >> 6) & 3;
            const int d = n_glob & 63;
            *(uint4*)&dst[((size_t)((b * NH + h) * SEQ) + t0 + row) * HD + d] =
                *(const uint4*)&T[row][c8];
        }
    } else {
        // V: transpose to T[n_local][m_local], then coalesced [D,T] stores.
        #pragma unroll
        for (int j = 0; j < 4; j++) {
            const int n_local = wc * 64 + j * 16 + l15;
            const float bj = bias[n0 + n_local];
            #pragma unroll
            for (int i = 0; i < 4; i++) {
                const int m_base = wr * 64 + i * 16 + l4 * 4;
                ushort4 pk;
                pk.x = f2bf(acc[i][j][0] + bj);
                pk.y = f2bf(acc[i][j][1] + bj);
                pk.z = f2bf(acc[i][j][2] + bj);
                pk.w = f2bf(acc[i][j][3] + bj);
                *(ushort4*)&T[n_local][m_base] = pk;
            }
        }
        __syncthreads();
        #pragma unroll
        for (int rr = 0; rr < 8; rr++) {
            const int fid = tid + rr * 256;
            const int row = fid >> 4;            // n_local 0..127
            const int c8  = (fid & 15) * 8;      // m_local chunk
            const int n_glob = n0 + row;
            const int h = (n_glob >> 6) & 3;
            const int d = n_glob & 63;
            *(uint4*)&Vtb[(size_t)((b * NH + h) * HD + d) * SEQ + t0 + c8] =
                *(const uint4*)&T[row][c8];
        }
    }
}

// ---------------------------------------------------------------------------
// MFMA flash attention (causal), S^T form, exp2 STATIC-MAX softmax,
// O^T = V^T * P^T — R7-measured structure (reg-staged K/V, double-buffered,
// loads for kt+1 issued BEFORE iteration kt's barrier -> in flight across
// barrier-wait + full compute; this hiding window is why reg-staging beat
// DMA staging, R8 post-mortem) + setprio around MFMA clusters + deferred-l.
// ---------------------------------------------------------------------------
__global__ __launch_bounds__(256, 4) void attn_mfma_kernel(
    const ushort_t* __restrict__ Qb, const ushort_t* __restrict__ Kb,
    const ushort_t* __restrict__ Vtb, ushort_t* __restrict__ out) {
    __shared__ ushort_t Ps[64 * 64];       // P tiles (wave-private 16-row bands)
    __shared__ ushort_t KV[4 * 64 * 64];   // K0 | K1 | V0 | V1 (8 KB each)

    const int tid = threadIdx.x;
    const int wv  = tid >> 6;
    const int ln  = tid & 63;
    const int l15 = ln & 15;
    const int l4  = ln >> 4;
    const int e   = l15 & 7;

    const int L  = blockIdx.x;
    const int g  = L & 255;
    const int s4 = L >> 8;               // dispatch wave 0..3
    const int v  = g >> 5;               // 0..7
    // longest-first; per-CU slot set {31-v, 16+v, 15-v, v} sums to 66 iters
    const int qb = (s4 == 0) ? (31 - v) : (s4 == 1) ? (16 + v) : (s4 == 2) ? (15 - v) : v;
    const int bh = g & 31;
    const int b  = bh >> 2;
    const int h  = bh & 3;

    // ---- Q fragments straight from global (B-operand: B[n=q][k]) ----
    const ushort_t* Qp = Qb + ((size_t)(bh * SEQ + qb * 64 + wv * 16 + l15)) * HD + l4 * 8;
    const bfrag bq0 = *(const bfrag*)Qp;
    const bfrag bq1 = *(const bfrag*)(Qp + 32);

    // ---- staging geometry ----
    const ushort_t* Kbase = Kb  + (size_t)bh * SEQ * HD;
    const ushort_t* Vbase = Vtb + (size_t)bh * HD * SEQ;
    const int srow  = tid >> 3;            // 0..31
    const int sc    = tid & 7;             // logical 16B-chunk
    const int goffA = srow * 64 + sc * 8;              // K global (ushorts)
    const int voffA = srow * SEQ + sc * 8;             // V global
    const int soffA = srow * 64 + ((sc ^ (srow & 7)) * 8);   // swizzled LDS

    // ---- fragment read offsets (precomputed, swizzled) ----
    const int kf0 = l15 * 64 + ((l4 ^ e) * 8);   // + n*1024 ; ^32 for k-chunk 1
    const int pf0 = (wv * 16 + l15) * 64 + ((l4 ^ e) * 8);
    const int pp  = e >> 1;
    const int pwb = (wv * 16 + l15) * 64 + (((l4 >> 1) ^ (e & 1)) * 8) + (l4 & 1) * 4;

    // ---- prologue: tile 0 -> regs -> LDS buf0 ; tile 1 -> regs ----
    uint4 kK0, kK1, kV0, kV1;
    kK0 = *(const uint4*)&Kbase[goffA];
    kK1 = *(const uint4*)&Kbase[goffA + 32 * 64];
    kV0 = *(const uint4*)&Vbase[voffA];
    kV1 = *(const uint4*)&Vbase[voffA + 32 * SEQ];
    *(uint4*)&KV[soffA]          = kK0;
    *(uint4*)&KV[soffA + 2048]   = kK1;
    *(uint4*)&KV[8192 + soffA]        = kV0;
    *(uint4*)&KV[8192 + soffA + 2048] = kV1;
    if (qb >= 1) {
        kK0 = *(const uint4*)&Kbase[4096 + goffA];
        kK1 = *(const uint4*)&Kbase[4096 + goffA + 32 * 64];
        kV0 = *(const uint4*)&Vbase[64 + voffA];
        kV1 = *(const uint4*)&Vbase[64 + voffA + 32 * SEQ];
    }

    ffrag o[4];   // O^T accumulator: o[n][r] = O^T[d = n*16+l4*4+r][q = l15]
    #pragma unroll
    for (int n = 0; n < 4; n++) o[n] = (ffrag){0.f, 0.f, 0.f, 0.f};
    float l_q = 0.f;                      // in-lane partial; shuffles at end
    const int qg_l = qb * 64 + wv * 16 + l15;

    for (int kt = 0; kt <= qb; kt++) {
        if (kt > 0) {
            // commit prefetched tile kt into buffer kt&1
            const int kb = (kt & 1) * 4096;
            *(uint4*)&KV[kb + soffA]          = kK0;
            *(uint4*)&KV[kb + soffA + 2048]   = kK1;
            *(uint4*)&KV[8192 + kb + soffA]        = kV0;
            *(uint4*)&KV[8192 + kb + soffA + 2048] = kV1;
            if (kt < qb) {   // issue loads for tile kt+1 (land during compute)
                const ushort_t* Kp  = Kbase + (kt + 1) * 4096;
                const ushort_t* Vtp = Vbase + (kt + 1) * 64;
                kK0 = *(const uint4*)&Kp[goffA];
                kK1 = *(const uint4*)&Kp[goffA + 32 * 64];
                kV0 = *(const uint4*)&Vtp[voffA];
                kV1 = *(const uint4*)&Vtp[voffA + 32 * SEQ];
            }
        }
        __syncthreads();   // the ONLY barrier in the iteration

        const ushort_t* Kbuf = KV + (kt & 1) * 4096;
        const ushort_t* Vbuf = KV + 8192 + (kt & 1) * 4096;

        // ---- S^T = K Q^T : s[n][r] = S[q=l15][k = n*16 + l4*4 + r] ----
        ffrag s[4];
        __builtin_amdgcn_s_setprio(1);
        #pragma unroll
        for (int n = 0; n < 4; n++) {
            const bfrag ak0 = *(const bfrag*)&Kbuf[n * 1024 + kf0];
            const bfrag ak1 = *(const bfrag*)&Kbuf[n * 1024 + (kf0 ^ 32)];
            ffrag z = (ffrag){0.f, 0.f, 0.f, 0.f};
            z = __builtin_amdgcn_mfma_f32_16x16x32_bf16(ak0, bq0, z, 0, 0, 0);
            z = __builtin_amdgcn_mfma_f32_16x16x32_bf16(ak1, bq1, z, 0, 0, 0);
            s[n] = z;
        }
        __builtin_amdgcn_s_setprio(0);
        if (kt == qb) {   // causal mask on the diagonal tile
            #pragma unroll
            for (int n = 0; n < 4; n++)
                #pragma unroll
                for (int r = 0; r < 4; r++)
                    if (kt * 64 + n * 16 + l4 * 4 + r > qg_l) s[n][r] = -INFINITY;
        }

        // ---- softmax (exp2 domain, static max): p = exp2(S'); exp2(-inf)=0 --
        #pragma unroll
        for (int n = 0; n < 4; n++)
            #pragma unroll
            for (int r = 0; r < 4; r++) {
                const float p = __builtin_amdgcn_exp2f(s[n][r]);
                s[n][r] = p;
                l_q += p;
            }

        // ---- pack P (bf16, A/B-layout rows q, swizzled, wave-private) ----
        #pragma unroll
        for (int n = 0; n < 4; n++) {
            uint2 pk;
            pk.x = pack2(s[n][0], s[n][1]);
            pk.y = pack2(s[n][2], s[n][3]);
            *(uint2*)&Ps[pwb + ((n ^ pp) << 4)] = pk;
        }

        // ---- O^T += V^T @ P^T ----
        const bfrag ap0 = *(const bfrag*)&Ps[pf0];
        const bfrag ap1 = *(const bfrag*)&Ps[pf0 ^ 32];
        __builtin_amdgcn_s_setprio(1);
        #pragma unroll
        for (int n = 0; n < 4; n++) {
            const bfrag av0 = *(const bfrag*)&Vbuf[n * 1024 + kf0];
            const bfrag av1 = *(const bfrag*)&Vbuf[n * 1024 + (kf0 ^ 32)];
            o[n] = __builtin_amdgcn_mfma_f32_16x16x32_bf16(av0, ap0, o[n], 0, 0, 0);
            o[n] = __builtin_amdgcn_mfma_f32_16x16x32_bf16(av1, ap1, o[n], 0, 0, 0);
        }
        __builtin_amdgcn_s_setprio(0);
    }

    // ---- deferred l reduction: l4-group partials are disjoint k-subsets ----
    l_q += __shfl_xor(l_q, 16);
    l_q += __shfl_xor(l_q, 32);

    // ---- normalize + store O (bf16, [B,T,C]): in-lane 1/l, vector stores ----
    const float li = 1.0f / l_q;
    const int tq = qb * 64 + wv * 16 + l15;        // this lane's q row
    ushort_t* op = out + (size_t)(b * SEQ + tq) * CH + h * HD;
    #pragma unroll
    for (int n = 0; n < 4; n++) {
        ushort4 pk;
        pk.x = f2bf(o[n][0] * li);
        pk.y = f2bf(o[n][1] * li);
        pk.z = f2bf(o[n][2] * li);
        pk.w = f2bf(o[n][3] * li);
        *(ushort4*)&op[n * 16 + l4 * 4] = pk;      // d = n*16 + l4*4 .. +3
    }
}

// ---------------------------------------------------------------------------
// Proj MFMA GEMM: attn_b @ WprojT^T + bproj -> fp32 out.
// 128x64 tile (4 waves: 2x2, each 64x32), grid 512 -> 2 blocks/CU.
// Epilogue transposes through LDS -> coalesced float4 stores (8/thread).
// ---------------------------------------------------------------------------
__global__ __launch_bounds__(256) void proj_mfma_kernel(
    const ushort_t* __restrict__ Ab, const ushort_t* __restrict__ Wt,
    const float* __restrict__ bias, float* __restrict__ O) {
    __shared__ __align__(16) char smem_raw[128 * 68 * 4];   // 34.8 KB
    ushort_t* As = (ushort_t*)smem_raw;
    ushort_t* Bs = As + 128 * GLS;

    const int tid = threadIdx.x;
    const int wv  = tid >> 6;
    const int ln  = tid & 63;
    const int l15 = ln & 15;
    const int l4  = ln >> 4;
    const int wr  = wv >> 1;          // 0..1 -> 64-row band
    const int wc  = wv & 1;           // 0..1 -> 32-col band
    const int n0  = blockIdx.x * 64;
    const int m0  = blockIdx.y * 128;

    ffrag acc[4][2];
    #pragma unroll
    for (int i = 0; i < 4; i++)
        #pragma unroll
        for (int j = 0; j < 2; j++) acc[i][j] = (ffrag){0.f, 0.f, 0.f, 0.f};

    for (int k0 = 0; k0 < CH; k0 += 64) {
        #pragma unroll
        for (int r = 0; r < 4; r++) {   // A: 128x64 = 1024 chunks
            const int fid = tid + r * 256;
            const int row = fid >> 3, c8 = (fid & 7) * 8;
            *(uint4*)&As[row * GLS + c8] = *(const uint4*)&Ab[(size_t)(m0 + row) * CH + k0 + c8];
        }
        #pragma unroll
        for (int r = 0; r < 2; r++) {   // B: 64x64 = 512 chunks
            const int fid = tid + r * 256;
            const int row = fid >> 3, c8 = (fid & 7) * 8;
            *(uint4*)&Bs[row * GLS + c8] = *(const uint4*)&Wt[(n0 + row) * CH + k0 + c8];
        }
        __syncthreads();
        #pragma unroll
        for (int kk = 0; kk < 64; kk += 32) {
            bfrag a[4], b[2];
            #pragma unroll
            for (int i = 0; i < 4; i++)
                a[i] = *(const bfrag*)&As[(wr * 64 + i * 16 + l15) * GLS + kk + l4 * 8];
            #pragma unroll
            for (int j = 0; j < 2; j++)
                b[j] = *(const bfrag*)&Bs[(wc * 32 + j * 16 + l15) * GLS + kk + l4 * 8];
            #pragma unroll
            for (int i = 0; i < 4; i++)
                #pragma unroll
                for (int j = 0; j < 2; j++)
                    acc[i][j] = __builtin_amdgcn_mfma_f32_16x16x32_bf16(a[i], b[j], acc[i][j], 0, 0, 0);
        }
        __syncthreads();
    }

    // ---- epilogue: transpose through LDS, coalesced float4 stores ----
    float (*Tf)[68] = (float(*)[68])smem_raw;   // last loop iter ended in barrier
    #pragma unroll
    for (int j = 0; j < 2; j++) {
        const int n_local = wc * 32 + j * 16 + l15;
        const float bj = bias[n0 + n_local];
        #pragma unroll
        for (int i = 0; i < 4; i++) {
            const int m_base = wr * 64 + i * 16 + l4 * 4;
            #pragma unroll
            for (int r = 0; r < 4; r++)
                Tf[m_base + r][n_local] = acc[i][j][r] + bj;
        }
    }
    __syncthreads();
    #pragma unroll
    for (int rr = 0; rr < 8; rr++) {
        const int fid = tid + rr * 256;
        const int row = fid >> 4;           // m_local 0..127
        const int c4  = (fid & 15) * 4;     // n_local chunk of 4 floats
        *(float4*)&O[(size_t)(m0 + row) * CH + n0 + c4] =
            *(const float4*)&Tf[row][c4];
    }
}

extern "C" void kernel_launch(void* const* d_in, const int* in_sizes, int n_in,
                              void* d_out, int out_size, void* d_ws, size_t ws_size,
                              hipStream_t stream) {
    const float* x     = (const float*)d_in[0];
    const float* Wqkv  = (const float*)d_in[1];
    const float* bqkv  = (const float*)d_in[2];
    const float* Wproj = (const float*)d_in[3];
    const float* bproj = (const float*)d_in[4];
    float* out = (float*)d_out;

    const size_t BHTD = (size_t)BATCH * NH * SEQ * HD;   // 4,194,304
    ushort_t* WqkvT  = (ushort_t*)d_ws;
    ushort_t* WprojT = WqkvT + (size_t)3 * CH * CH;
    ushort_t* Qb     = WprojT + (size_t)CH * CH;
    ushort_t* Kb     = Qb + BHTD;
    ushort_t* Vtb    = Kb + BHTD;
    ushort_t* attn_b = Vtb + BHTD;
    ushort_t* xb     = attn_b;          // alias: xb dead before attn writes

    const int M = BATCH * SEQ;   // 16384

    {
        const int total = XN8 + WQN + WPN;          // 786,432
        prep_kernel<<<(total + 255) / 256, 256, 0, stream>>>(x, Wqkv, Wproj, xb, WqkvT, WprojT);
    }
    {
        dim3 grid((3 * CH) / 128, M / 128);
        qkv_mfma_kernel<<<grid, 256, 0, stream>>>(xb, WqkvT, bqkv, Qb, Kb, Vtb);
    }
    {
        attn_mfma_kernel<<<dim3(NQB * BATCH * NH), 256, 0, stream>>>(Qb, Kb, Vtb, attn_b);
    }
    {
        dim3 grid(CH / 64, M / 128);
        proj_mfma_kernel<<<grid, 256, 0, stream>>>(attn_b, WprojT, bproj, out);
    }
}

// Round 10
// 127.845 us; speedup vs baseline: 1.0754x; 1.0371x over previous
//
#include <hip/hip_runtime.h>
#include <hip/hip_bf16.h>
#include <math.h>

#define BATCH 8
#define SEQ   2048
#define CH    256
#define NH    4
#define HD    64
#define NQB   (SEQ / 64)      // 32 query tiles of 64
// Q pre-scale: 64^-0.5 * log2(e)  (softmax runs in exp2 domain)
#define QSCALE 0.18033688011112042f

typedef short  bfrag __attribute__((ext_vector_type(8)));  // 8 bf16 (4 VGPRs)
typedef float  ffrag __attribute__((ext_vector_type(4)));  // 4 fp32 acc
typedef unsigned short ushort_t;
typedef unsigned int u32;

__device__ __forceinline__ unsigned short f2bf(float f) {
    union { float f; unsigned int u; } v; v.f = f;
    unsigned int r = v.u + 0x7FFF + ((v.u >> 16) & 1);   // RNE
    return (unsigned short)(r >> 16);
}
__device__ __forceinline__ unsigned int pack2(float a, float b) {
    const __hip_bfloat162 p = __float22bfloat162_rn(make_float2(a, b));
    return *(const unsigned int*)&p;
}
// async global->LDS, 16B/lane. LDS base must be wave-uniform; global per-lane.
__device__ __forceinline__ void gload16(const ushort_t* g, ushort_t* l) {
    __builtin_amdgcn_global_load_lds(
        (const __attribute__((address_space(1))) u32*)g,
        (__attribute__((address_space(3))) u32*)l, 16, 0, 0);
}

// ---------------------------------------------------------------------------
// Prep: x -> bf16 [M][C] (vectorized x8), Wqkv/Wproj -> transposed bf16.
// xb aliases attn_b in workspace (dead until attn writes, which is post-qkv).
// ---------------------------------------------------------------------------
#define WQN (CH * 3 * CH)            // 196608
#define WPN (CH * CH)                // 65536
#define XN  (BATCH * SEQ * CH)       // 4,194,304
#define XN8 (XN / 8)                 // 524,288

__global__ __launch_bounds__(256) void prep_kernel(
    const float* __restrict__ x,
    const float* __restrict__ Wqkv, const float* __restrict__ Wproj,
    ushort_t* __restrict__ xb,
    ushort_t* __restrict__ WqkvT, ushort_t* __restrict__ WprojT) {
    const int fid = blockIdx.x * 256 + threadIdx.x;
    if (fid < XN8) {
        const float4 a = *(const float4*)&x[(size_t)fid * 8];
        const float4 c = *(const float4*)&x[(size_t)fid * 8 + 4];
        uint4 pk;
        pk.x = pack2(a.x, a.y); pk.y = pack2(a.z, a.w);
        pk.z = pack2(c.x, c.y); pk.w = pack2(c.z, c.w);
        *(uint4*)&xb[(size_t)fid * 8] = pk;
    } else {
        const int id = fid - XN8;
        if (id < WQN) {
            const int n = id >> 8, k = id & 255;
            WqkvT[n * CH + k] = f2bf(Wqkv[k * (3 * CH) + n]);
        } else if (id < WQN + WPN) {
            const int i = id - WQN;
            const int n = i >> 8, k = i & 255;
            WprojT[n * CH + k] = f2bf(Wproj[k * CH + n]);
        }
    }
}

// ---------------------------------------------------------------------------
// QKV MFMA GEMM: xb bf16 @ WqkvT^T + bqkv -> bf16 Q(*QSCALE),K [BH,T,D],
// V^T [BH,D,T]. 128x128 tile, 4 waves each 64x64, BK=64.
// Staging via global_load_lds width=16 (async); linear LDS + pre-swizzled
// global source + swizzled fragment reads (verified R7).
// XCD-aware work remap (T1): 1D grid 768 (=6 n-tiles x 128 m-tiles),
// work = (bid%8)*96 + bid/8 (bijective, 768%8==0). Each XCD gets 16
// consecutive m-tiles x all 6 n-tiles -> the shared 64KB A-panels become
// L2-resident (1 MB/XCD << 4 MB L2) instead of being re-fetched 6x from L3.
// ---------------------------------------------------------------------------
#define GLS 72   // LDS row stride in ushorts (proj kernel only)

__global__ __launch_bounds__(256) void qkv_mfma_kernel(
    const ushort_t* __restrict__ xb, const ushort_t* __restrict__ Wt,
    const float* __restrict__ bias,
    ushort_t* __restrict__ Qb, ushort_t* __restrict__ Kb,
    ushort_t* __restrict__ Vtb) {
    __shared__ ushort_t smem[128 * 136];   // As[0,8K) Bs[8K,16K) ; epilogue T[128][136]
    ushort_t* As = smem;
    ushort_t* Bs = smem + 128 * 64;

    const int tid = threadIdx.x;
    const int wv  = tid >> 6;
    const int ln  = tid & 63;
    const int l15 = ln & 15;
    const int l4  = ln >> 4;
    const int e   = l15 & 7;
    const int wr  = wv >> 1;          // wave row 0..1
    const int wc  = wv & 1;           // wave col 0..1

    // XCD-chunked bijective remap: same-m0 blocks land on the same XCD.
    const int bid  = blockIdx.x;                  // 0..767
    const int work = (bid & 7) * 96 + (bid >> 3); // XCD k <- works [96k,96k+96)
    const int mt   = work / 6;                    // m-tile 0..127 (n-fastest)
    const int nt   = work - mt * 6;               // n-tile 0..5
    const int n0   = nt * 128;
    const int m0   = mt * 128;

    // staging geometry: each wave moves 4x1KB chunks per matrix per K-step.
    const int grow = ln >> 3;                         // row within 8-row chunk
    const int swz  = ((ln & 7) ^ grow) * 8;           // pre-swizzled src chunk

    ffrag acc[4][4];
    #pragma unroll
    for (int i = 0; i < 4; i++)
        #pragma unroll
        for (int j = 0; j < 4; j++) acc[i][j] = (ffrag){0.f, 0.f, 0.f, 0.f};

    for (int k0 = 0; k0 < CH; k0 += 64) {
        #pragma unroll
        for (int i = 0; i < 4; i++) {
            const int rowA = (i * 4 + wv) * 8 + grow;       // 0..127
            gload16(&xb[(size_t)(m0 + rowA) * CH + k0 + swz], &As[(i * 4 + wv) * 512]);
            gload16(&Wt[(size_t)(n0 + rowA) * CH + k0 + swz], &Bs[(i * 4 + wv) * 512]);
        }
        __syncthreads();   // drains vmcnt (incl. global_load_lds) at barrier
        #pragma unroll
        for (int kk = 0; kk < 64; kk += 32) {
            bfrag a[4], b[4];
            #pragma unroll
            for (int i = 0; i < 4; i++) {
                const int R = wr * 64 + i * 16 + l15;       // R&7 == e
                a[i] = *(const bfrag*)&As[R * 64 + ((((kk >> 3) + l4) ^ e) * 8)];
            }
            #pragma unroll
            for (int j = 0; j < 4; j++) {
                const int R = wc * 64 + j * 16 + l15;       // R&7 == e
                b[j] = *(const bfrag*)&Bs[R * 64 + ((((kk >> 3) + l4) ^ e) * 8)];
            }
            #pragma unroll
            for (int i = 0; i < 4; i++)
                #pragma unroll
                for (int j = 0; j < 4; j++)
                    acc[i][j] = __builtin_amdgcn_mfma_f32_16x16x32_bf16(a[i], b[j], acc[i][j], 0, 0, 0);
        }
        __syncthreads();
    }

    const int mat = n0 >> 8;                 // block-uniform: 0=Q 1=K 2=V
    const int b   = m0 >> 11;                // block-uniform
    const int t0  = m0 & (SEQ - 1);
    ushort_t (*T)[136] = (ushort_t(*)[136])smem;

    if (mat < 2) {
        // Q/K: transpose to T[t_local][n_local], then coalesced [T,D] stores.
        const float sc = (mat == 0) ? QSCALE : 1.0f;
        #pragma unroll
        for (int j = 0; j < 4; j++) {
            const int n_local = wc * 64 + j * 16 + l15;
            const float bj = bias[n0 + n_local];
            #pragma unroll
            for (int i = 0; i < 4; i++) {
                const int m_base = wr * 64 + i * 16 + l4 * 4;
                #pragma unroll
                for (int r = 0; r < 4; r++)
                    T[m_base + r][n_local] = f2bf((acc[i][j][r] + bj) * sc);
            }
        }
        __syncthreads();
        ushort_t* dst = (mat == 0) ? Qb : Kb;
        #pragma unroll
        for (int rr = 0; rr < 8; rr++) {
            const int fid = tid + rr * 256;
            const int row = fid >> 4;            // t_local 0..127
            const int c8  = (fid & 15) * 8;      // n_local chunk
            const int n_glob = n0 + c8;
            const int h = (n_glob >> 6) & 3;
            const int d = n_glob & 63;
            *(uint4*)&dst[((size_t)((b * NH + h) * SEQ) + t0 + row) * HD + d] =
                *(const uint4*)&T[row][c8];
        }
    } else {
        // V: transpose to T[n_local][m_local], then coalesced [D,T] stores.
        #pragma unroll
        for (int j = 0; j < 4; j++) {
            const int n_local = wc * 64 + j * 16 + l15;
            const float bj = bias[n0 + n_local];
            #pragma unroll
            for (int i = 0; i < 4; i++) {
                const int m_base = wr * 64 + i * 16 + l4 * 4;
                ushort4 pk;
                pk.x = f2bf(acc[i][j][0] + bj);
                pk.y = f2bf(acc[i][j][1] + bj);
                pk.z = f2bf(acc[i][j][2] + bj);
                pk.w = f2bf(acc[i][j][3] + bj);
                *(ushort4*)&T[n_local][m_base] = pk;
            }
        }
        __syncthreads();
        #pragma unroll
        for (int rr = 0; rr < 8; rr++) {
            const int fid = tid + rr * 256;
            const int row = fid >> 4;            // n_local 0..127
            const int c8  = (fid & 15) * 8;      // m_local chunk
            const int n_glob = n0 + row;
            const int h = (n_glob >> 6) & 3;
            const int d = n_glob & 63;
            *(uint4*)&Vtb[(size_t)((b * NH + h) * HD + d) * SEQ + t0 + c8] =
                *(const uint4*)&T[row][c8];
        }
    }
}

// ---------------------------------------------------------------------------
// MFMA flash attention (causal), S^T form, exp2 STATIC-MAX softmax,
// O^T = V^T * P^T — R7/R9-measured structure (reg-staged K/V, double-
// buffered, loads for kt+1 issued BEFORE iteration kt's barrier -> in flight
// across barrier-wait + full compute; this hiding window is why reg-staging
// beat DMA staging, R8 post-mortem) + setprio + deferred-l.
// K/V is already XCD-local: blocks sharing bh are == bh (mod 8).
// ---------------------------------------------------------------------------
__global__ __launch_bounds__(256, 4) void attn_mfma_kernel(
    const ushort_t* __restrict__ Qb, const ushort_t* __restrict__ Kb,
    const ushort_t* __restrict__ Vtb, ushort_t* __restrict__ out) {
    __shared__ ushort_t Ps[64 * 64];       // P tiles (wave-private 16-row bands)
    __shared__ ushort_t KV[4 * 64 * 64];   // K0 | K1 | V0 | V1 (8 KB each)

    const int tid = threadIdx.x;
    const int wv  = tid >> 6;
    const int ln  = tid & 63;
    const int l15 = ln & 15;
    const int l4  = ln >> 4;
    const int e   = l15 & 7;

    const int L  = blockIdx.x;
    const int g  = L & 255;
    const int s4 = L >> 8;               // dispatch wave 0..3
    const int v  = g >> 5;               // 0..7
    // longest-first; per-CU slot set {31-v, 16+v, 15-v, v} sums to 66 iters
    const int qb = (s4 == 0) ? (31 - v) : (s4 == 1) ? (16 + v) : (s4 == 2) ? (15 - v) : v;
    const int bh = g & 31;
    const int b  = bh >> 2;
    const int h  = bh & 3;

    // ---- Q fragments straight from global (B-operand: B[n=q][k]) ----
    const ushort_t* Qp = Qb + ((size_t)(bh * SEQ + qb * 64 + wv * 16 + l15)) * HD + l4 * 8;
    const bfrag bq0 = *(const bfrag*)Qp;
    const bfrag bq1 = *(const bfrag*)(Qp + 32);

    // ---- staging geometry ----
    const ushort_t* Kbase = Kb  + (size_t)bh * SEQ * HD;
    const ushort_t* Vbase = Vtb + (size_t)bh * HD * SEQ;
    const int srow  = tid >> 3;            // 0..31
    const int sc    = tid & 7;             // logical 16B-chunk
    const int goffA = srow * 64 + sc * 8;              // K global (ushorts)
    const int voffA = srow * SEQ + sc * 8;             // V global
    const int soffA = srow * 64 + ((sc ^ (srow & 7)) * 8);   // swizzled LDS

    // ---- fragment read offsets (precomputed, swizzled) ----
    const int kf0 = l15 * 64 + ((l4 ^ e) * 8);   // + n*1024 ; ^32 for k-chunk 1
    const int pf0 = (wv * 16 + l15) * 64 + ((l4 ^ e) * 8);
    const int pp  = e >> 1;
    const int pwb = (wv * 16 + l15) * 64 + (((l4 >> 1) ^ (e & 1)) * 8) + (l4 & 1) * 4;

    // ---- prologue: tile 0 -> regs -> LDS buf0 ; tile 1 -> regs ----
    uint4 kK0, kK1, kV0, kV1;
    kK0 = *(const uint4*)&Kbase[goffA];
    kK1 = *(const uint4*)&Kbase[goffA + 32 * 64];
    kV0 = *(const uint4*)&Vbase[voffA];
    kV1 = *(const uint4*)&Vbase[voffA + 32 * SEQ];
    *(uint4*)&KV[soffA]          = kK0;
    *(uint4*)&KV[soffA + 2048]   = kK1;
    *(uint4*)&KV[8192 + soffA]        = kV0;
    *(uint4*)&KV[8192 + soffA + 2048] = kV1;
    if (qb >= 1) {
        kK0 = *(const uint4*)&Kbase[4096 + goffA];
        kK1 = *(const uint4*)&Kbase[4096 + goffA + 32 * 64];
        kV0 = *(const uint4*)&Vbase[64 + voffA];
        kV1 = *(const uint4*)&Vbase[64 + voffA + 32 * SEQ];
    }

    ffrag o[4];   // O^T accumulator: o[n][r] = O^T[d = n*16+l4*4+r][q = l15]
    #pragma unroll
    for (int n = 0; n < 4; n++) o[n] = (ffrag){0.f, 0.f, 0.f, 0.f};
    float l_q = 0.f;                      // in-lane partial; shuffles at end
    const int qg_l = qb * 64 + wv * 16 + l15;

    for (int kt = 0; kt <= qb; kt++) {
        if (kt > 0) {
            // commit prefetched tile kt into buffer kt&1
            const int kb = (kt & 1) * 4096;
            *(uint4*)&KV[kb + soffA]          = kK0;
            *(uint4*)&KV[kb + soffA + 2048]   = kK1;
            *(uint4*)&KV[8192 + kb + soffA]        = kV0;
            *(uint4*)&KV[8192 + kb + soffA + 2048] = kV1;
            if (kt < qb) {   // issue loads for tile kt+1 (land during compute)
                const ushort_t* Kp  = Kbase + (kt + 1) * 4096;
                const ushort_t* Vtp = Vbase + (kt + 1) * 64;
                kK0 = *(const uint4*)&Kp[goffA];
                kK1 = *(const uint4*)&Kp[goffA + 32 * 64];
                kV0 = *(const uint4*)&Vtp[voffA];
                kV1 = *(const uint4*)&Vtp[voffA + 32 * SEQ];
            }
        }
        __syncthreads();   // the ONLY barrier in the iteration

        const ushort_t* Kbuf = KV + (kt & 1) * 4096;
        const ushort_t* Vbuf = KV + 8192 + (kt & 1) * 4096;

        // ---- S^T = K Q^T : s[n][r] = S[q=l15][k = n*16 + l4*4 + r] ----
        ffrag s[4];
        __builtin_amdgcn_s_setprio(1);
        #pragma unroll
        for (int n = 0; n < 4; n++) {
            const bfrag ak0 = *(const bfrag*)&Kbuf[n * 1024 + kf0];
            const bfrag ak1 = *(const bfrag*)&Kbuf[n * 1024 + (kf0 ^ 32)];
            ffrag z = (ffrag){0.f, 0.f, 0.f, 0.f};
            z = __builtin_amdgcn_mfma_f32_16x16x32_bf16(ak0, bq0, z, 0, 0, 0);
            z = __builtin_amdgcn_mfma_f32_16x16x32_bf16(ak1, bq1, z, 0, 0, 0);
            s[n] = z;
        }
        __builtin_amdgcn_s_setprio(0);
        if (kt == qb) {   // causal mask on the diagonal tile
            #pragma unroll
            for (int n = 0; n < 4; n++)
                #pragma unroll
                for (int r = 0; r < 4; r++)
                    if (kt * 64 + n * 16 + l4 * 4 + r > qg_l) s[n][r] = -INFINITY;
        }

        // ---- softmax (exp2 domain, static max): p = exp2(S'); exp2(-inf)=0 --
        #pragma unroll
        for (int n = 0; n < 4; n++)
            #pragma unroll
            for (int r = 0; r < 4; r++) {
                const float p = __builtin_amdgcn_exp2f(s[n][r]);
                s[n][r] = p;
                l_q += p;
            }

        // ---- pack P (bf16, A/B-layout rows q, swizzled, wave-private) ----
        #pragma unroll
        for (int n = 0; n < 4; n++) {
            uint2 pk;
            pk.x = pack2(s[n][0], s[n][1]);
            pk.y = pack2(s[n][2], s[n][3]);
            *(uint2*)&Ps[pwb + ((n ^ pp) << 4)] = pk;
        }

        // ---- O^T += V^T @ P^T ----
        const bfrag ap0 = *(const bfrag*)&Ps[pf0];
        const bfrag ap1 = *(const bfrag*)&Ps[pf0 ^ 32];
        __builtin_amdgcn_s_setprio(1);
        #pragma unroll
        for (int n = 0; n < 4; n++) {
            const bfrag av0 = *(const bfrag*)&Vbuf[n * 1024 + kf0];
            const bfrag av1 = *(const bfrag*)&Vbuf[n * 1024 + (kf0 ^ 32)];
            o[n] = __builtin_amdgcn_mfma_f32_16x16x32_bf16(av0, ap0, o[n], 0, 0, 0);
            o[n] = __builtin_amdgcn_mfma_f32_16x16x32_bf16(av1, ap1, o[n], 0, 0, 0);
        }
        __builtin_amdgcn_s_setprio(0);
    }

    // ---- deferred l reduction: l4-group partials are disjoint k-subsets ----
    l_q += __shfl_xor(l_q, 16);
    l_q += __shfl_xor(l_q, 32);

    // ---- normalize + store O (bf16, [B,T,C]): in-lane 1/l, vector stores ----
    const float li = 1.0f / l_q;
    const int tq = qb * 64 + wv * 16 + l15;        // this lane's q row
    ushort_t* op = out + (size_t)(b * SEQ + tq) * CH + h * HD;
    #pragma unroll
    for (int n = 0; n < 4; n++) {
        ushort4 pk;
        pk.x = f2bf(o[n][0] * li);
        pk.y = f2bf(o[n][1] * li);
        pk.z = f2bf(o[n][2] * li);
        pk.w = f2bf(o[n][3] * li);
        *(ushort4*)&op[n * 16 + l4 * 4] = pk;      // d = n*16 + l4*4 .. +3
    }
}

// ---------------------------------------------------------------------------
// Proj MFMA GEMM: attn_b @ WprojT^T + bproj -> fp32 out.
// 128x64 tile (4 waves: 2x2, each 64x32). XCD-aware work remap (T1):
// 1D grid 512 (=4 n-tiles x 128 m-tiles), work = (bid%8)*64 + bid/8
// (bijective, 512%8==0) -> each XCD gets 16 m-tiles x 4 n-tiles, A-panels
// L2-resident. Epilogue transposes through LDS -> coalesced float4 stores.
// ---------------------------------------------------------------------------
__global__ __launch_bounds__(256) void proj_mfma_kernel(
    const ushort_t* __restrict__ Ab, const ushort_t* __restrict__ Wt,
    const float* __restrict__ bias, float* __restrict__ O) {
    __shared__ __align__(16) char smem_raw[128 * 68 * 4];   // 34.8 KB
    ushort_t* As = (ushort_t*)smem_raw;
    ushort_t* Bs = As + 128 * GLS;

    const int tid = threadIdx.x;
    const int wv  = tid >> 6;
    const int ln  = tid & 63;
    const int l15 = ln & 15;
    const int l4  = ln >> 4;
    const int wr  = wv >> 1;          // 0..1 -> 64-row band
    const int wc  = wv & 1;           // 0..1 -> 32-col band

    // XCD-chunked bijective remap: same-m0 blocks land on the same XCD.
    const int bid  = blockIdx.x;                  // 0..511
    const int work = (bid & 7) * 64 + (bid >> 3);
    const int mt   = work >> 2;                   // m-tile 0..127 (n-fastest)
    const int nt   = work & 3;                    // n-tile 0..3
    const int n0   = nt * 64;
    const int m0   = mt * 128;

    ffrag acc[4][2];
    #pragma unroll
    for (int i = 0; i < 4; i++)
        #pragma unroll
        for (int j = 0; j < 2; j++) acc[i][j] = (ffrag){0.f, 0.f, 0.f, 0.f};

    for (int k0 = 0; k0 < CH; k0 += 64) {
        #pragma unroll
        for (int r = 0; r < 4; r++) {   // A: 128x64 = 1024 chunks
            const int fid = tid + r * 256;
            const int row = fid >> 3, c8 = (fid & 7) * 8;
            *(uint4*)&As[row * GLS + c8] = *(const uint4*)&Ab[(size_t)(m0 + row) * CH + k0 + c8];
        }
        #pragma unroll
        for (int r = 0; r < 2; r++) {   // B: 64x64 = 512 chunks
            const int fid = tid + r * 256;
            const int row = fid >> 3, c8 = (fid & 7) * 8;
            *(uint4*)&Bs[row * GLS + c8] = *(const uint4*)&Wt[(n0 + row) * CH + k0 + c8];
        }
        __syncthreads();
        #pragma unroll
        for (int kk = 0; kk < 64; kk += 32) {
            bfrag a[4], b[2];
            #pragma unroll
            for (int i = 0; i < 4; i++)
                a[i] = *(const bfrag*)&As[(wr * 64 + i * 16 + l15) * GLS + kk + l4 * 8];
            #pragma unroll
            for (int j = 0; j < 2; j++)
                b[j] = *(const bfrag*)&Bs[(wc * 32 + j * 16 + l15) * GLS + kk + l4 * 8];
            #pragma unroll
            for (int i = 0; i < 4; i++)
                #pragma unroll
                for (int j = 0; j < 2; j++)
                    acc[i][j] = __builtin_amdgcn_mfma_f32_16x16x32_bf16(a[i], b[j], acc[i][j], 0, 0, 0);
        }
        __syncthreads();
    }

    // ---- epilogue: transpose through LDS, coalesced float4 stores ----
    float (*Tf)[68] = (float(*)[68])smem_raw;   // last loop iter ended in barrier
    #pragma unroll
    for (int j = 0; j < 2; j++) {
        const int n_local = wc * 32 + j * 16 + l15;
        const float bj = bias[n0 + n_local];
        #pragma unroll
        for (int i = 0; i < 4; i++) {
            const int m_base = wr * 64 + i * 16 + l4 * 4;
            #pragma unroll
            for (int r = 0; r < 4; r++)
                Tf[m_base + r][n_local] = acc[i][j][r] + bj;
        }
    }
    __syncthreads();
    #pragma unroll
    for (int rr = 0; rr < 8; rr++) {
        const int fid = tid + rr * 256;
        const int row = fid >> 4;           // m_local 0..127
        const int c4  = (fid & 15) * 4;     // n_local chunk of 4 floats
        *(float4*)&O[(size_t)(m0 + row) * CH + n0 + c4] =
            *(const float4*)&Tf[row][c4];
    }
}

extern "C" void kernel_launch(void* const* d_in, const int* in_sizes, int n_in,
                              void* d_out, int out_size, void* d_ws, size_t ws_size,
                              hipStream_t stream) {
    const float* x     = (const float*)d_in[0];
    const float* Wqkv  = (const float*)d_in[1];
    const float* bqkv  = (const float*)d_in[2];
    const float* Wproj = (const float*)d_in[3];
    const float* bproj = (const float*)d_in[4];
    float* out = (float*)d_out;

    const size_t BHTD = (size_t)BATCH * NH * SEQ * HD;   // 4,194,304
    ushort_t* WqkvT  = (ushort_t*)d_ws;
    ushort_t* WprojT = WqkvT + (size_t)3 * CH * CH;
    ushort_t* Qb     = WprojT + (size_t)CH * CH;
    ushort_t* Kb     = Qb + BHTD;
    ushort_t* Vtb    = Kb + BHTD;
    ushort_t* attn_b = Vtb + BHTD;
    ushort_t* xb     = attn_b;          // alias: xb dead before attn writes

    {
        const int total = XN8 + WQN + WPN;          // 786,432
        prep_kernel<<<(total + 255) / 256, 256, 0, stream>>>(x, Wqkv, Wproj, xb, WqkvT, WprojT);
    }
    {
        qkv_mfma_kernel<<<dim3(768), 256, 0, stream>>>(xb, WqkvT, bqkv, Qb, Kb, Vtb);
    }
    {
        attn_mfma_kernel<<<dim3(NQB * BATCH * NH), 256, 0, stream>>>(Qb, Kb, Vtb, attn_b);
    }
    {
        proj_mfma_kernel<<<dim3(512), 256, 0, stream>>>(attn_b, WprojT, bproj, out);
    }
}

// Round 11
// 125.257 us; speedup vs baseline: 1.0976x; 1.0207x over previous
//
#include <hip/hip_runtime.h>
#include <hip/hip_bf16.h>
#include <math.h>

#define BATCH 8
#define SEQ   2048
#define CH    256
#define NH    4
#define HD    64
#define NQB   (SEQ / 64)      // 32 query tiles of 64
// Q pre-scale: 64^-0.5 * log2(e)  (softmax runs in exp2 domain)
#define QSCALE 0.18033688011112042f

typedef short  bfrag  __attribute__((ext_vector_type(8)));   // 8 bf16 (4 VGPRs)
typedef float  ffrag  __attribute__((ext_vector_type(4)));   // 4 fp32 acc
typedef float  facc16 __attribute__((ext_vector_type(16)));  // 32x32 acc
typedef unsigned short ushort_t;
typedef unsigned int u32;

__device__ __forceinline__ unsigned short f2bf(float f) {
    union { float f; unsigned int u; } v; v.f = f;
    unsigned int r = v.u + 0x7FFF + ((v.u >> 16) & 1);   // RNE
    return (unsigned short)(r >> 16);
}
__device__ __forceinline__ unsigned int pack2(float a, float b) {
    const __hip_bfloat162 p = __float22bfloat162_rn(make_float2(a, b));
    return *(const unsigned int*)&p;
}
// async global->LDS, 16B/lane. LDS base must be wave-uniform; global per-lane.
__device__ __forceinline__ void gload16(const ushort_t* g, ushort_t* l) {
    __builtin_amdgcn_global_load_lds(
        (const __attribute__((address_space(1))) u32*)g,
        (__attribute__((address_space(3))) u32*)l, 16, 0, 0);
}
// half-swap across lane<32 / lane>=32: after call,
//   a = {a.lo, b.lo}  (lane i<32: old a[i]; lane 32+i: old b[i])
//   b = {a.hi, b.hi}  (lane i<32: old a[32+i]; lane 32+i: old b[32+i])
__device__ __forceinline__ void half_swap(u32& a, u32& b) {
#if __has_builtin(__builtin_amdgcn_permlane32_swap)
    auto r = __builtin_amdgcn_permlane32_swap(a, b, false, false);
    a = r[0]; b = r[1];
#else
    const u32 sa = (u32)__shfl_xor((int)a, 32);
    const u32 sb = (u32)__shfl_xor((int)b, 32);
    const bool hi = (threadIdx.x & 32) != 0;
    const u32 na = hi ? sb : a;
    const u32 nb = hi ? b : sa;
    a = na; b = nb;
#endif
}

// ---------------------------------------------------------------------------
// Prep: x -> bf16 [M][C] (vectorized x8), Wqkv/Wproj -> transposed bf16.
// xb aliases attn_b in workspace (dead until attn writes, which is post-qkv).
// ---------------------------------------------------------------------------
#define WQN (CH * 3 * CH)            // 196608
#define WPN (CH * CH)                // 65536
#define XN  (BATCH * SEQ * CH)       // 4,194,304
#define XN8 (XN / 8)                 // 524,288

__global__ __launch_bounds__(256) void prep_kernel(
    const float* __restrict__ x,
    const float* __restrict__ Wqkv, const float* __restrict__ Wproj,
    ushort_t* __restrict__ xb,
    ushort_t* __restrict__ WqkvT, ushort_t* __restrict__ WprojT) {
    const int fid = blockIdx.x * 256 + threadIdx.x;
    if (fid < XN8) {
        const float4 a = *(const float4*)&x[(size_t)fid * 8];
        const float4 c = *(const float4*)&x[(size_t)fid * 8 + 4];
        uint4 pk;
        pk.x = pack2(a.x, a.y); pk.y = pack2(a.z, a.w);
        pk.z = pack2(c.x, c.y); pk.w = pack2(c.z, c.w);
        *(uint4*)&xb[(size_t)fid * 8] = pk;
    } else {
        const int id = fid - XN8;
        if (id < WQN) {
            const int n = id >> 8, k = id & 255;
            WqkvT[n * CH + k] = f2bf(Wqkv[k * (3 * CH) + n]);
        } else if (id < WQN + WPN) {
            const int i = id - WQN;
            const int n = i >> 8, k = i & 255;
            WprojT[n * CH + k] = f2bf(Wproj[k * CH + n]);
        }
    }
}

// ---------------------------------------------------------------------------
// QKV MFMA GEMM (unchanged from R10): global_load_lds staging, both-sides
// swizzle, XCD-chunked bijective remap (768 = 6n x 128m; work=(bid%8)*96+bid/8).
// ---------------------------------------------------------------------------
#define GLS 72   // LDS row stride in ushorts (proj kernel only)

__global__ __launch_bounds__(256) void qkv_mfma_kernel(
    const ushort_t* __restrict__ xb, const ushort_t* __restrict__ Wt,
    const float* __restrict__ bias,
    ushort_t* __restrict__ Qb, ushort_t* __restrict__ Kb,
    ushort_t* __restrict__ Vtb) {
    __shared__ ushort_t smem[128 * 136];   // As[0,8K) Bs[8K,16K) ; epilogue T[128][136]
    ushort_t* As = smem;
    ushort_t* Bs = smem + 128 * 64;

    const int tid = threadIdx.x;
    const int wv  = tid >> 6;
    const int ln  = tid & 63;
    const int l15 = ln & 15;
    const int l4  = ln >> 4;
    const int e   = l15 & 7;
    const int wr  = wv >> 1;          // wave row 0..1
    const int wc  = wv & 1;           // wave col 0..1

    // XCD-chunked bijective remap: same-m0 blocks land on the same XCD.
    const int bid  = blockIdx.x;                  // 0..767
    const int work = (bid & 7) * 96 + (bid >> 3); // XCD k <- works [96k,96k+96)
    const int mt   = work / 6;                    // m-tile 0..127 (n-fastest)
    const int nt   = work - mt * 6;               // n-tile 0..5
    const int n0   = nt * 128;
    const int m0   = mt * 128;

    // staging geometry: each wave moves 4x1KB chunks per matrix per K-step.
    const int grow = ln >> 3;                         // row within 8-row chunk
    const int swz  = ((ln & 7) ^ grow) * 8;           // pre-swizzled src chunk

    ffrag acc[4][4];
    #pragma unroll
    for (int i = 0; i < 4; i++)
        #pragma unroll
        for (int j = 0; j < 4; j++) acc[i][j] = (ffrag){0.f, 0.f, 0.f, 0.f};

    for (int k0 = 0; k0 < CH; k0 += 64) {
        #pragma unroll
        for (int i = 0; i < 4; i++) {
            const int rowA = (i * 4 + wv) * 8 + grow;       // 0..127
            gload16(&xb[(size_t)(m0 + rowA) * CH + k0 + swz], &As[(i * 4 + wv) * 512]);
            gload16(&Wt[(size_t)(n0 + rowA) * CH + k0 + swz], &Bs[(i * 4 + wv) * 512]);
        }
        __syncthreads();   // drains vmcnt (incl. global_load_lds) at barrier
        #pragma unroll
        for (int kk = 0; kk < 64; kk += 32) {
            bfrag a[4], b[4];
            #pragma unroll
            for (int i = 0; i < 4; i++) {
                const int R = wr * 64 + i * 16 + l15;       // R&7 == e
                a[i] = *(const bfrag*)&As[R * 64 + ((((kk >> 3) + l4) ^ e) * 8)];
            }
            #pragma unroll
            for (int j = 0; j < 4; j++) {
                const int R = wc * 64 + j * 16 + l15;       // R&7 == e
                b[j] = *(const bfrag*)&Bs[R * 64 + ((((kk >> 3) + l4) ^ e) * 8)];
            }
            #pragma unroll
            for (int i = 0; i < 4; i++)
                #pragma unroll
                for (int j = 0; j < 4; j++)
                    acc[i][j] = __builtin_amdgcn_mfma_f32_16x16x32_bf16(a[i], b[j], acc[i][j], 0, 0, 0);
        }
        __syncthreads();
    }

    const int mat = n0 >> 8;                 // block-uniform: 0=Q 1=K 2=V
    const int b   = m0 >> 11;                // block-uniform
    const int t0  = m0 & (SEQ - 1);
    ushort_t (*T)[136] = (ushort_t(*)[136])smem;

    if (mat < 2) {
        // Q/K: transpose to T[t_local][n_local], then coalesced [T,D] stores.
        const float sc = (mat == 0) ? QSCALE : 1.0f;
        #pragma unroll
        for (int j = 0; j < 4; j++) {
            const int n_local = wc * 64 + j * 16 + l15;
            const float bj = bias[n0 + n_local];
            #pragma unroll
            for (int i = 0; i < 4; i++) {
                const int m_base = wr * 64 + i * 16 + l4 * 4;
                #pragma unroll
                for (int r = 0; r < 4; r++)
                    T[m_base + r][n_local] = f2bf((acc[i][j][r] + bj) * sc);
            }
        }
        __syncthreads();
        ushort_t* dst = (mat == 0) ? Qb : Kb;
        #pragma unroll
        for (int rr = 0; rr < 8; rr++) {
            const int fid = tid + rr * 256;
            const int row = fid >> 4;            // t_local 0..127
            const int c8  = (fid & 15) * 8;      // n_local chunk
            const int n_glob = n0 + c8;
            const int h = (n_glob >> 6) & 3;
            const int d = n_glob & 63;
            *(uint4*)&dst[((size_t)((b * NH + h) * SEQ) + t0 + row) * HD + d] =
                *(const uint4*)&T[row][c8];
        }
    } else {
        // V: transpose to T[n_local][m_local], then coalesced [D,T] stores.
        #pragma unroll
        for (int j = 0; j < 4; j++) {
            const int n_local = wc * 64 + j * 16 + l15;
            const float bj = bias[n0 + n_local];
            #pragma unroll
            for (int i = 0; i < 4; i++) {
                const int m_base = wr * 64 + i * 16 + l4 * 4;
                ushort4 pk;
                pk.x = f2bf(acc[i][j][0] + bj);
                pk.y = f2bf(acc[i][j][1] + bj);
                pk.z = f2bf(acc[i][j][2] + bj);
                pk.w = f2bf(acc[i][j][3] + bj);
                *(ushort4*)&T[n_local][m_base] = pk;
            }
        }
        __syncthreads();
        #pragma unroll
        for (int rr = 0; rr < 8; rr++) {
            const int fid = tid + rr * 256;
            const int row = fid >> 4;            // n_local 0..127
            const int c8  = (fid & 15) * 8;      // m_local chunk
            const int n_glob = n0 + row;
            const int h = (n_glob >> 6) & 3;
            const int d = n_glob & 63;
            *(uint4*)&Vtb[(size_t)((b * NH + h) * HD + d) * SEQ + t0 + c8] =
                *(const uint4*)&T[row][c8];
        }
    }
}

// ---------------------------------------------------------------------------
// MFMA flash attention (causal) — 32x32x16 k-split restructure.
// Each wave (qh=wv>>1, kh=wv&1) owns 32q x 32k of the 64x64 tile:
//  * QK: S^T(32k x 32q) = mfma_32x32x16(A=K, B=Q) x4 over D=64.
//    A layout: m=lane&31, k-chunk=(lane>>5)*8 (generalizes verified 16x16
//    pattern); C/D: col(q)=lane&31, row(k)=(r&3)+8*(r>>2)+4*(lane>>5)
//    [m74/m101-verified].
//  * P stays IN REGISTER: acc k-distribution maps to the PV B-operand via 2
//    half_swaps per 16-k step (lane hi-half holds k+4 offsets; swap fills
//    each lane's contiguous 8-k run). No Ps LDS buffer, no P round-trip.
//  * PV: O^T(32d x 32q) partial over the wave's 32k; k-halves summed once in
//    the epilogue via LDS (exact same additions, reordered).
// LDS/block-iter: 32KB (K 16 + V 16) vs 88KB before; K/V frag redundancy
// 4x -> 2x; MFMA count halved at same FLOPs. Staging identical to R10
// (reg-staged, prefetch-before-barrier — R8 showed DMA-after-barrier loses).
// ---------------------------------------------------------------------------
__global__ __launch_bounds__(256, 4) void attn_mfma_kernel(
    const ushort_t* __restrict__ Qb, const ushort_t* __restrict__ Kb,
    const ushort_t* __restrict__ Vtb, ushort_t* __restrict__ out) {
    __shared__ ushort_t KV[4 * 64 * 64];   // K0 | K1 | V0 | V1 (8 KB each)

    const int tid = threadIdx.x;
    const int wv  = tid >> 6;
    const int ln  = tid & 63;
    const int l31 = ln & 31;
    const int hi  = ln >> 5;
    const int qh  = wv >> 1;             // q-half 0..1 (rows qh*32..+31)
    const int kh  = wv & 1;              // k-half 0..1 (cols kh*32..+31)
    const int e8  = l31 & 7;

    const int L  = blockIdx.x;
    const int g  = L & 255;
    const int s4 = L >> 8;               // dispatch wave 0..3
    const int v  = g >> 5;               // 0..7
    // longest-first; per-CU slot set {31-v, 16+v, 15-v, v} sums to 66 iters
    const int qb = (s4 == 0) ? (31 - v) : (s4 == 1) ? (16 + v) : (s4 == 2) ? (15 - v) : v;
    const int bh = g & 31;
    const int b  = bh >> 2;
    const int h  = bh & 3;

    // ---- Q fragments (B-operand: n=q=lane&31, d-chunk=(lane>>5)*8 +16s) ----
    const ushort_t* Qp = Qb + ((size_t)(bh * SEQ + qb * 64 + qh * 32 + l31)) * HD + hi * 8;
    bfrag bq[4];
    #pragma unroll
    for (int s = 0; s < 4; s++) bq[s] = *(const bfrag*)(Qp + s * 16);

    // ---- staging geometry (identical to R10) ----
    const ushort_t* Kbase = Kb  + (size_t)bh * SEQ * HD;
    const ushort_t* Vbase = Vtb + (size_t)bh * HD * SEQ;
    const int srow  = tid >> 3;            // 0..31
    const int sc    = tid & 7;             // logical 16B-chunk
    const int goffA = srow * 64 + sc * 8;              // K global (ushorts)
    const int voffA = srow * SEQ + sc * 8;             // V global
    const int soffA = srow * 64 + ((sc ^ (srow & 7)) * 8);   // swizzled LDS

    // ---- K fragment base: row = kh*32 + l31 (row&7 == e8) ----
    const int krow = kh * 32 + l31;

    // ---- prologue: tile 0 -> regs -> LDS buf0 ; tile 1 -> regs ----
    uint4 kK0, kK1, kV0, kV1;
    kK0 = *(const uint4*)&Kbase[goffA];
    kK1 = *(const uint4*)&Kbase[goffA + 32 * 64];
    kV0 = *(const uint4*)&Vbase[voffA];
    kV1 = *(const uint4*)&Vbase[voffA + 32 * SEQ];
    *(uint4*)&KV[soffA]          = kK0;
    *(uint4*)&KV[soffA + 2048]   = kK1;
    *(uint4*)&KV[8192 + soffA]        = kV0;
    *(uint4*)&KV[8192 + soffA + 2048] = kV1;
    if (qb >= 1) {
        kK0 = *(const uint4*)&Kbase[4096 + goffA];
        kK1 = *(const uint4*)&Kbase[4096 + goffA + 32 * 64];
        kV0 = *(const uint4*)&Vbase[64 + voffA];
        kV1 = *(const uint4*)&Vbase[64 + voffA + 32 * SEQ];
    }

    facc16 o0, o1;   // O^T partials: o{t}[r] = O^T[d=t*32+(r&3)+8(r>>2)+4hi][q]
    #pragma unroll
    for (int r = 0; r < 16; r++) { o0[r] = 0.f; o1[r] = 0.f; }
    float l_q = 0.f;                      // in-lane partial over this wave's k
    const int qg_l = qb * 64 + qh * 32 + l31;   // this lane's global q row

    for (int kt = 0; kt <= qb; kt++) {
        if (kt > 0) {
            const int kb = (kt & 1) * 4096;
            *(uint4*)&KV[kb + soffA]          = kK0;
            *(uint4*)&KV[kb + soffA + 2048]   = kK1;
            *(uint4*)&KV[8192 + kb + soffA]        = kV0;
            *(uint4*)&KV[8192 + kb + soffA + 2048] = kV1;
            if (kt < qb) {   // issue loads for tile kt+1 (land during compute)
                const ushort_t* Kp  = Kbase + (kt + 1) * 4096;
                const ushort_t* Vtp = Vbase + (kt + 1) * 64;
                kK0 = *(const uint4*)&Kp[goffA];
                kK1 = *(const uint4*)&Kp[goffA + 32 * 64];
                kV0 = *(const uint4*)&Vtp[voffA];
                kV1 = *(const uint4*)&Vtp[voffA + 32 * SEQ];
            }
        }
        __syncthreads();   // the ONLY barrier in the iteration

        const ushort_t* Kbuf = KV + (kt & 1) * 4096;
        const ushort_t* Vbuf = KV + 8192 + (kt & 1) * 4096;

        // ---- S^T = K Q^T over the wave's 32k: 4 MFMAs (D=64, K=16 each) ----
        facc16 s_;
        #pragma unroll
        for (int r = 0; r < 16; r++) s_[r] = 0.f;
        __builtin_amdgcn_s_setprio(1);
        #pragma unroll
        for (int s = 0; s < 4; s++) {
            const bfrag ak = *(const bfrag*)&Kbuf[krow * 64 + (((2 * s + hi) ^ e8) * 8)];
            s_ = __builtin_amdgcn_mfma_f32_32x32x16_bf16(ak, bq[s], s_, 0, 0, 0);
        }
        __builtin_amdgcn_s_setprio(0);

        if (kt == qb) {   // causal mask on the diagonal tile
            #pragma unroll
            for (int r = 0; r < 16; r++) {
                const int kabs = kt * 64 + kh * 32 + (r & 3) + 8 * (r >> 2) + 4 * hi;
                if (kabs > qg_l) s_[r] = -INFINITY;
            }
        }

        // ---- softmax (exp2 domain, static max) ----
        float p[16];
        #pragma unroll
        for (int r = 0; r < 16; r++) {
            p[r] = __builtin_amdgcn_exp2f(s_[r]);
            l_q += p[r];
        }

        // ---- P -> PV B-operand fully in register (2 half_swaps / k-step) ---
        // lane holds k_local = (r&3)+8(r>>2)+4hi; B-frag needs k = 8hi..8hi+7
        // (contiguous) per 16-k step. half_swap(A0,B0) yields words w0,w2;
        // half_swap(A1,B1) yields w1,w3 (derivation in session notes).
        __builtin_amdgcn_s_setprio(1);
        #pragma unroll
        for (int gstep = 0; gstep < 2; gstep++) {   // k 16*gstep .. +15 (local)
            u32 A0 = pack2(p[8 * gstep + 0], p[8 * gstep + 1]);
            u32 A1 = pack2(p[8 * gstep + 2], p[8 * gstep + 3]);
            u32 B0 = pack2(p[8 * gstep + 4], p[8 * gstep + 5]);
            u32 B1 = pack2(p[8 * gstep + 6], p[8 * gstep + 7]);
            half_swap(A0, B0);   // A0 -> w0, B0 -> w2
            half_swap(A1, B1);   // A1 -> w1, B1 -> w3
            union { u32 w[4]; bfrag f; } pa;
            pa.w[0] = A0; pa.w[1] = A1; pa.w[2] = B0; pa.w[3] = B1;
            const int vc = ((kh * 4 + 2 * gstep + hi) ^ e8) * 8;
            const bfrag av0 = *(const bfrag*)&Vbuf[l31 * 64 + vc];
            const bfrag av1 = *(const bfrag*)&Vbuf[(32 + l31) * 64 + vc];
            o0 = __builtin_amdgcn_mfma_f32_32x32x16_bf16(av0, pa.f, o0, 0, 0, 0);
            o1 = __builtin_amdgcn_mfma_f32_32x32x16_bf16(av1, pa.f, o1, 0, 0, 0);
        }
        __builtin_amdgcn_s_setprio(0);
    }

    // ---- merge hi-halves of l (disjoint k-subsets of the same q) ----
    l_q += __shfl_xor(l_q, 32);

    // ---- epilogue: k-half waves combine O and l via LDS (one-time) ----
    __syncthreads();                       // all K/V reads done; reuse KV
    float* Xf = (float*)KV;
    const int xbase = qh * 2304 + ln * 36;      // stride 36 floats (pad)
    if (kh) {
        #pragma unroll
        for (int gr = 0; gr < 4; gr++) {
            *(float4*)&Xf[xbase + gr * 4] =
                make_float4(o0[gr * 4], o0[gr * 4 + 1], o0[gr * 4 + 2], o0[gr * 4 + 3]);
            *(float4*)&Xf[xbase + 16 + gr * 4] =
                make_float4(o1[gr * 4], o1[gr * 4 + 1], o1[gr * 4 + 2], o1[gr * 4 + 3]);
        }
        Xf[4608 + qh * 64 + ln] = l_q;
    }
    __syncthreads();
    if (!kh) {
        #pragma unroll
        for (int gr = 0; gr < 4; gr++) {
            const float4 v0 = *(const float4*)&Xf[xbase + gr * 4];
            o0[gr * 4]     += v0.x; o0[gr * 4 + 1] += v0.y;
            o0[gr * 4 + 2] += v0.z; o0[gr * 4 + 3] += v0.w;
            const float4 v1 = *(const float4*)&Xf[xbase + 16 + gr * 4];
            o1[gr * 4]     += v1.x; o1[gr * 4 + 1] += v1.y;
            o1[gr * 4 + 2] += v1.z; o1[gr * 4 + 3] += v1.w;
        }
        l_q += Xf[4608 + qh * 64 + ln];

        const float li = 1.0f / l_q;
        const int tq = qb * 64 + qh * 32 + l31;
        ushort_t* op = out + (size_t)(b * SEQ + tq) * CH + h * HD;
        #pragma unroll
        for (int gr = 0; gr < 4; gr++) {
            const int d0a = gr * 8 + 4 * hi;            // tile 0
            ushort4 pk0;
            pk0.x = f2bf(o0[gr * 4]     * li);
            pk0.y = f2bf(o0[gr * 4 + 1] * li);
            pk0.z = f2bf(o0[gr * 4 + 2] * li);
            pk0.w = f2bf(o0[gr * 4 + 3] * li);
            *(ushort4*)&op[d0a] = pk0;
            ushort4 pk1;                                 // tile 1: d += 32
            pk1.x = f2bf(o1[gr * 4]     * li);
            pk1.y = f2bf(o1[gr * 4 + 1] * li);
            pk1.z = f2bf(o1[gr * 4 + 2] * li);
            pk1.w = f2bf(o1[gr * 4 + 3] * li);
            *(ushort4*)&op[32 + d0a] = pk1;
        }
    }
}

// ---------------------------------------------------------------------------
// Proj MFMA GEMM (unchanged from R10): XCD-chunked remap (512 = 4n x 128m),
// LDS-transpose epilogue with coalesced float4 stores.
// ---------------------------------------------------------------------------
__global__ __launch_bounds__(256) void proj_mfma_kernel(
    const ushort_t* __restrict__ Ab, const ushort_t* __restrict__ Wt,
    const float* __restrict__ bias, float* __restrict__ O) {
    __shared__ __align__(16) char smem_raw[128 * 68 * 4];   // 34.8 KB
    ushort_t* As = (ushort_t*)smem_raw;
    ushort_t* Bs = As + 128 * GLS;

    const int tid = threadIdx.x;
    const int wv  = tid >> 6;
    const int ln  = tid & 63;
    const int l15 = ln & 15;
    const int l4  = ln >> 4;
    const int wr  = wv >> 1;          // 0..1 -> 64-row band
    const int wc  = wv & 1;           // 0..1 -> 32-col band

    // XCD-chunked bijective remap: same-m0 blocks land on the same XCD.
    const int bid  = blockIdx.x;                  // 0..511
    const int work = (bid & 7) * 64 + (bid >> 3);
    const int mt   = work >> 2;                   // m-tile 0..127 (n-fastest)
    const int nt   = work & 3;                    // n-tile 0..3
    const int n0   = nt * 64;
    const int m0   = mt * 128;

    ffrag acc[4][2];
    #pragma unroll
    for (int i = 0; i < 4; i++)
        #pragma unroll
        for (int j = 0; j < 2; j++) acc[i][j] = (ffrag){0.f, 0.f, 0.f, 0.f};

    for (int k0 = 0; k0 < CH; k0 += 64) {
        #pragma unroll
        for (int r = 0; r < 4; r++) {   // A: 128x64 = 1024 chunks
            const int fid = tid + r * 256;
            const int row = fid >> 3, c8 = (fid & 7) * 8;
            *(uint4*)&As[row * GLS + c8] = *(const uint4*)&Ab[(size_t)(m0 + row) * CH + k0 + c8];
        }
        #pragma unroll
        for (int r = 0; r < 2; r++) {   // B: 64x64 = 512 chunks
            const int fid = tid + r * 256;
            const int row = fid >> 3, c8 = (fid & 7) * 8;
            *(uint4*)&Bs[row * GLS + c8] = *(const uint4*)&Wt[(n0 + row) * CH + k0 + c8];
        }
        __syncthreads();
        #pragma unroll
        for (int kk = 0; kk < 64; kk += 32) {
            bfrag a[4], b[2];
            #pragma unroll
            for (int i = 0; i < 4; i++)
                a[i] = *(const bfrag*)&As[(wr * 64 + i * 16 + l15) * GLS + kk + l4 * 8];
            #pragma unroll
            for (int j = 0; j < 2; j++)
                b[j] = *(const bfrag*)&Bs[(wc * 32 + j * 16 + l15) * GLS + kk + l4 * 8];
            #pragma unroll
            for (int i = 0; i < 4; i++)
                #pragma unroll
                for (int j = 0; j < 2; j++)
                    acc[i][j] = __builtin_amdgcn_mfma_f32_16x16x32_bf16(a[i], b[j], acc[i][j], 0, 0, 0);
        }
        __syncthreads();
    }

    // ---- epilogue: transpose through LDS, coalesced float4 stores ----
    float (*Tf)[68] = (float(*)[68])smem_raw;   // last loop iter ended in barrier
    #pragma unroll
    for (int j = 0; j < 2; j++) {
        const int n_local = wc * 32 + j * 16 + l15;
        const float bj = bias[n0 + n_local];
        #pragma unroll
        for (int i = 0; i < 4; i++) {
            const int m_base = wr * 64 + i * 16 + l4 * 4;
            #pragma unroll
            for (int r = 0; r < 4; r++)
                Tf[m_base + r][n_local] = acc[i][j][r] + bj;
        }
    }
    __syncthreads();
    #pragma unroll
    for (int rr = 0; rr < 8; rr++) {
        const int fid = tid + rr * 256;
        const int row = fid >> 4;           // m_local 0..127
        const int c4  = (fid & 15) * 4;     // n_local chunk of 4 floats
        *(float4*)&O[(size_t)(m0 + row) * CH + n0 + c4] =
            *(const float4*)&Tf[row][c4];
    }
}

extern "C" void kernel_launch(void* const* d_in, const int* in_sizes, int n_in,
                              void* d_out, int out_size, void* d_ws, size_t ws_size,
                              hipStream_t stream) {
    const float* x     = (const float*)d_in[0];
    const float* Wqkv  = (const float*)d_in[1];
    const float* bqkv  = (const float*)d_in[2];
    const float* Wproj = (const float*)d_in[3];
    const float* bproj = (const float*)d_in[4];
    float* out = (float*)d_out;

    const size_t BHTD = (size_t)BATCH * NH * SEQ * HD;   // 4,194,304
    ushort_t* WqkvT  = (ushort_t*)d_ws;
    ushort_t* WprojT = WqkvT + (size_t)3 * CH * CH;
    ushort_t* Qb     = WprojT + (size_t)CH * CH;
    ushort_t* Kb     = Qb + BHTD;
    ushort_t* Vtb    = Kb + BHTD;
    ushort_t* attn_b = Vtb + BHTD;
    ushort_t* xb     = attn_b;          // alias: xb dead before attn writes

    {
        const int total = XN8 + WQN + WPN;          // 786,432
        prep_kernel<<<(total + 255) / 256, 256, 0, stream>>>(x, Wqkv, Wproj, xb, WqkvT, WprojT);
    }
    {
        qkv_mfma_kernel<<<dim3(768), 256, 0, stream>>>(xb, WqkvT, bqkv, Qb, Kb, Vtb);
    }
    {
        attn_mfma_kernel<<<dim3(NQB * BATCH * NH), 256, 0, stream>>>(Qb, Kb, Vtb, attn_b);
    }
    {
        proj_mfma_kernel<<<dim3(512), 256, 0, stream>>>(attn_b, WprojT, bproj, out);
    }
}